// Round 2
// baseline (2040.759 us; speedup 1.0000x reference)
//
#include <hip/hip_runtime.h>
#include <stdint.h>

// Problem dims (fixed by the reference)
constexpr int B_ = 2, S_ = 2048, E_ = 1024, H_ = 16, D_ = 64;
constexpr int M_ = B_ * S_;              // 4096 rows
constexpr size_t ME_ = (size_t)M_ * E_;  // 4,194,304

// ---------------------------------------------------------------------------
// Kernel 1: fused QKV projection (all fp32).
// C[m][n] = sum_k X[m][k] * W_qkv[n][k] + b_qkv[n], n in [0, 3E).
// Each 64-wide n-tile lies fully inside one projection (E % 64 == 0), so the
// block picks its X pointer from {q,k,v}. Output stored fp32 as [proj][B,H,S,D].
// ---------------------------------------------------------------------------
__global__ __launch_bounds__(256) void qkv_proj_kernel(
    const float* __restrict__ q,
    const float* __restrict__ k,
    const float* __restrict__ v,
    const float* __restrict__ Wqkv,
    const float* __restrict__ bqkv,
    float* __restrict__ ws)
{
  __shared__ __align__(16) float As[16][64];  // [k][m]
  __shared__ __align__(16) float Bs[16][64];  // [k][n]
  const int t = threadIdx.x;
  const int m0 = blockIdx.x * 64;
  const int n0g = blockIdx.y * 64;           // global col in [0, 3072)
  const int proj = n0g >> 10;                // /E
  const int nloc = n0g & (E_ - 1);
  const float* X = (proj == 0) ? q : (proj == 1) ? k : v;
  const int tx = t & 15, ty = t >> 4;
  const int lr = t >> 2;                     // tile row 0..63
  const int lk = (t & 3) * 4;                // k offset 0..12
  float acc[4][4] = {};

  for (int k0 = 0; k0 < E_; k0 += 16) {
    {
      const float4 ua = *(const float4*)(X + (size_t)(m0 + lr) * E_ + k0 + lk);
      As[lk + 0][lr] = ua.x; As[lk + 1][lr] = ua.y;
      As[lk + 2][lr] = ua.z; As[lk + 3][lr] = ua.w;
      const float4 uw = *(const float4*)(Wqkv + (size_t)(n0g + lr) * E_ + k0 + lk);
      Bs[lk + 0][lr] = uw.x; Bs[lk + 1][lr] = uw.y;
      Bs[lk + 2][lr] = uw.z; Bs[lk + 3][lr] = uw.w;
    }
    __syncthreads();
#pragma unroll
    for (int kk = 0; kk < 16; ++kk) {
      const float4 a = *(const float4*)&As[kk][ty * 4];
      const float4 b = *(const float4*)&Bs[kk][tx * 4];
      acc[0][0] += a.x * b.x; acc[0][1] += a.x * b.y; acc[0][2] += a.x * b.z; acc[0][3] += a.x * b.w;
      acc[1][0] += a.y * b.x; acc[1][1] += a.y * b.y; acc[1][2] += a.y * b.z; acc[1][3] += a.y * b.w;
      acc[2][0] += a.z * b.x; acc[2][1] += a.z * b.y; acc[2][2] += a.z * b.z; acc[2][3] += a.z * b.w;
      acc[3][0] += a.w * b.x; acc[3][1] += a.w * b.y; acc[3][2] += a.w * b.z; acc[3][3] += a.w * b.w;
    }
    __syncthreads();
  }

  const int h = nloc >> 6;                   // D = 64
  const int nc = tx * 4;
  const float b0 = bqkv[n0g + nc + 0];
  const float b1 = bqkv[n0g + nc + 1];
  const float b2 = bqkv[n0g + nc + 2];
  const float b3 = bqkv[n0g + nc + 3];
  float* dst = ws + (size_t)proj * ME_;
#pragma unroll
  for (int i = 0; i < 4; ++i) {
    const int m = m0 + ty * 4 + i;
    const int bb = m >> 11;                  // /S
    const int s = m & (S_ - 1);
    float4 o = make_float4(acc[i][0] + b0, acc[i][1] + b1, acc[i][2] + b2, acc[i][3] + b3);
    *(float4*)&dst[(((size_t)bb * H_ + h) * S_ + s) * D_ + nc] = o;
  }
}

// ---------------------------------------------------------------------------
// Kernel 2: flash-style attention. Block = 256 threads = (b,h, 16 q-rows).
// Streams 64-key tiles with online softmax; O acc in registers (1 d-col x 4 q).
// ---------------------------------------------------------------------------
__global__ __launch_bounds__(256) void attn_kernel(
    const float* __restrict__ ws,
    const int* __restrict__ mask,
    float* __restrict__ AO)
{
  const float* Qp = ws;
  const float* Kp = ws + ME_;
  const float* Vp = ws + 2 * ME_;

  __shared__ __align__(16) float Qs[16][64];
  __shared__ __align__(16) float Ks[64][68];  // [k][d], padded (272B rows, 16B-aligned)
  __shared__ __align__(16) float Vt[64][68];  // [d][k], transposed
  __shared__ __align__(16) float Sc[16][68];  // scores / probs
  __shared__ float m_sh[16], l_sh[16], al_sh[16];

  const int t = threadIdx.x;
  const int bh = blockIdx.y;                 // 0..31
  const int b = bh >> 4, hh = bh & (H_ - 1);
  const int q0 = blockIdx.x * 16;
  const size_t hb = (size_t)bh * S_ * D_;

  // stage Q tile (16x64 fp32, 1 float4/thread)
  {
    const int qr = t >> 4, dc = (t & 15) * 4;
    *(float4*)&Qs[qr][dc] = *(const float4*)&Qp[hb + (size_t)(q0 + qr) * D_ + dc];
  }
  if (t < 16) { m_sh[t] = -INFINITY; l_sh[t] = 0.f; }

  const int kc = t & 63;                     // key col (phase 1) == d col (phase 3)
  const int qg = t >> 6;                     // wave id -> q group
  float acc[4] = {0.f, 0.f, 0.f, 0.f};

  for (int kt = 0; kt < S_; kt += 64) {
    __syncthreads();  // protect Ks/Vt/Sc from previous iteration readers
    // stage K (row-major) and V (transposed) tiles
#pragma unroll
    for (int r = 0; r < 4; ++r) {
      const int e = t + 256 * r;
      const int kr = e >> 4, ds = (e & 15) * 4;
      const float4 kv = *(const float4*)&Kp[hb + (size_t)(kt + kr) * D_ + ds];
      Ks[kr][ds + 0] = kv.x; Ks[kr][ds + 1] = kv.y; Ks[kr][ds + 2] = kv.z; Ks[kr][ds + 3] = kv.w;
      const float4 vv = *(const float4*)&Vp[hb + (size_t)(kt + kr) * D_ + ds];
      Vt[ds + 0][kr] = vv.x; Vt[ds + 1][kr] = vv.y; Vt[ds + 2][kr] = vv.z; Vt[ds + 3][kr] = vv.w;
    }
    __syncthreads();

    // phase 1: scores for 4 q-rows at key kc
    {
      float s0 = 0.f, s1 = 0.f, s2 = 0.f, s3 = 0.f;
#pragma unroll
      for (int d4 = 0; d4 < 64; d4 += 4) {
        const float4 kf = *(const float4*)&Ks[kc][d4];
        const float4 qa = *(const float4*)&Qs[qg * 4 + 0][d4];
        const float4 qb = *(const float4*)&Qs[qg * 4 + 1][d4];
        const float4 qc = *(const float4*)&Qs[qg * 4 + 2][d4];
        const float4 qd = *(const float4*)&Qs[qg * 4 + 3][d4];
        s0 += qa.x * kf.x + qa.y * kf.y + qa.z * kf.z + qa.w * kf.w;
        s1 += qb.x * kf.x + qb.y * kf.y + qb.z * kf.z + qb.w * kf.w;
        s2 += qc.x * kf.x + qc.y * kf.y + qc.z * kf.z + qc.w * kf.w;
        s3 += qd.x * kf.x + qd.y * kf.y + qd.z * kf.z + qd.w * kf.w;
      }
      const bool msk = (mask[b * S_ + kt + kc] == 0);
      Sc[qg * 4 + 0][kc] = msk ? -1e20f : s0;
      Sc[qg * 4 + 1][kc] = msk ? -1e20f : s1;
      Sc[qg * 4 + 2][kc] = msk ? -1e20f : s2;
      Sc[qg * 4 + 3][kc] = msk ? -1e20f : s3;
    }
    __syncthreads();

    // phase 2: online-softmax stats, one thread per q-row
    if (t < 16) {
      const float mo = m_sh[t];
      float mx = mo;
      for (int kk = 0; kk < 64; ++kk) mx = fmaxf(mx, Sc[t][kk]);
      const float al = expf(mo - mx);        // first tile: exp(-inf)=0
      float sum = 0.f;
      for (int kk = 0; kk < 64; ++kk) {
        const float p = expf(Sc[t][kk] - mx);
        Sc[t][kk] = p;
        sum += p;
      }
      m_sh[t] = mx;
      l_sh[t] = l_sh[t] * al + sum;
      al_sh[t] = al;
    }
    __syncthreads();

    // phase 3: O rescale + PV accumulate (thread owns d=kc, 4 q-rows)
    {
      acc[0] *= al_sh[qg * 4 + 0];
      acc[1] *= al_sh[qg * 4 + 1];
      acc[2] *= al_sh[qg * 4 + 2];
      acc[3] *= al_sh[qg * 4 + 3];
#pragma unroll
      for (int k4 = 0; k4 < 64; k4 += 4) {
        const float4 vv = *(const float4*)&Vt[kc][k4];
        const float4 p0 = *(const float4*)&Sc[qg * 4 + 0][k4];
        const float4 p1 = *(const float4*)&Sc[qg * 4 + 1][k4];
        const float4 p2 = *(const float4*)&Sc[qg * 4 + 2][k4];
        const float4 p3 = *(const float4*)&Sc[qg * 4 + 3][k4];
        acc[0] += p0.x * vv.x + p0.y * vv.y + p0.z * vv.z + p0.w * vv.w;
        acc[1] += p1.x * vv.x + p1.y * vv.y + p1.z * vv.z + p1.w * vv.w;
        acc[2] += p2.x * vv.x + p2.y * vv.y + p2.z * vv.z + p2.w * vv.w;
        acc[3] += p3.x * vv.x + p3.y * vv.y + p3.z * vv.z + p3.w * vv.w;
      }
    }
  }

  // epilogue: normalize and write [B,S,E] fp32
#pragma unroll
  for (int i = 0; i < 4; ++i) {
    const int qq = qg * 4 + i;
    const float linv = 1.0f / l_sh[qq];
    AO[((size_t)(b * S_ + q0 + qq)) * E_ + hh * D_ + kc] = acc[i] * linv;
  }
}

// ---------------------------------------------------------------------------
// Kernel 3: output projection. out[m][n] = sum_k AO[m][k]*W_out[n][k] + b_out[n]
// ---------------------------------------------------------------------------
__global__ __launch_bounds__(256) void out_proj_kernel(
    const float* __restrict__ AO,
    const float* __restrict__ Wout,
    const float* __restrict__ bout,
    float* __restrict__ out)
{
  __shared__ __align__(16) float As[16][64];
  __shared__ __align__(16) float Bs[16][64];
  const int t = threadIdx.x;
  const int m0 = blockIdx.x * 64;
  const int n0 = blockIdx.y * 64;
  const int tx = t & 15, ty = t >> 4;
  const int lr = t >> 2;
  const int lk = (t & 3) * 4;
  float acc[4][4] = {};

  for (int k0 = 0; k0 < E_; k0 += 16) {
    {
      const float4 la = *(const float4*)&AO[(size_t)(m0 + lr) * E_ + k0 + lk];
      As[lk + 0][lr] = la.x; As[lk + 1][lr] = la.y;
      As[lk + 2][lr] = la.z; As[lk + 3][lr] = la.w;
      const float4 uw = *(const float4*)(Wout + (size_t)(n0 + lr) * E_ + k0 + lk);
      Bs[lk + 0][lr] = uw.x; Bs[lk + 1][lr] = uw.y;
      Bs[lk + 2][lr] = uw.z; Bs[lk + 3][lr] = uw.w;
    }
    __syncthreads();
#pragma unroll
    for (int kk = 0; kk < 16; ++kk) {
      const float4 a = *(const float4*)&As[kk][ty * 4];
      const float4 b = *(const float4*)&Bs[kk][tx * 4];
      acc[0][0] += a.x * b.x; acc[0][1] += a.x * b.y; acc[0][2] += a.x * b.z; acc[0][3] += a.x * b.w;
      acc[1][0] += a.y * b.x; acc[1][1] += a.y * b.y; acc[1][2] += a.y * b.z; acc[1][3] += a.y * b.w;
      acc[2][0] += a.z * b.x; acc[2][1] += a.z * b.y; acc[2][2] += a.z * b.z; acc[2][3] += a.z * b.w;
      acc[3][0] += a.w * b.x; acc[3][1] += a.w * b.y; acc[3][2] += a.w * b.z; acc[3][3] += a.w * b.w;
    }
    __syncthreads();
  }

  const int nc = tx * 4;
  const float b0 = bout[n0 + nc + 0];
  const float b1 = bout[n0 + nc + 1];
  const float b2 = bout[n0 + nc + 2];
  const float b3 = bout[n0 + nc + 3];
#pragma unroll
  for (int i = 0; i < 4; ++i) {
    const int m = m0 + ty * 4 + i;
    float4 o = make_float4(acc[i][0] + b0, acc[i][1] + b1, acc[i][2] + b2, acc[i][3] + b3);
    *(float4*)&out[(size_t)m * E_ + n0 + nc] = o;
  }
}

// ---------------------------------------------------------------------------
extern "C" void kernel_launch(void* const* d_in, const int* in_sizes, int n_in,
                              void* d_out, int out_size, void* d_ws, size_t ws_size,
                              hipStream_t stream) {
  const float* q    = (const float*)d_in[0];
  const float* k    = (const float*)d_in[1];
  const float* v    = (const float*)d_in[2];
  const int*   mask = (const int*)d_in[3];
  const float* Wqkv = (const float*)d_in[4];
  const float* bqkv = (const float*)d_in[5];
  const float* Wout = (const float*)d_in[6];
  const float* bout = (const float*)d_in[7];

  float* ws = (float*)d_ws;           // [Qp | Kp | Vp | AO], each M_*E_ fp32
  float* AO = ws + 3 * ME_;
  float* out = (float*)d_out;

  hipLaunchKernelGGL(qkv_proj_kernel, dim3(M_ / 64, 48), dim3(256), 0, stream,
                     q, k, v, Wqkv, bqkv, ws);
  hipLaunchKernelGGL(attn_kernel, dim3(S_ / 16, B_ * H_), dim3(256), 0, stream,
                     ws, mask, AO);
  hipLaunchKernelGGL(out_proj_kernel, dim3(M_ / 64, E_ / 64), dim3(256), 0, stream,
                     AO, Wout, bout, out);
}

// Round 3
// 1526.439 us; speedup vs baseline: 1.3369x; 1.3369x over previous
//
#include <hip/hip_runtime.h>
#include <stdint.h>

// Problem dims (fixed by the reference)
constexpr int B_ = 2, S_ = 2048, E_ = 1024, H_ = 16, D_ = 64;
constexpr int M_ = B_ * S_;              // 4096 rows
constexpr size_t ME_ = (size_t)M_ * E_;  // 4,194,304

// ---------------------------------------------------------------------------
// Kernel 1: fused QKV projection (all fp32).
// ---------------------------------------------------------------------------
__global__ __launch_bounds__(256) void qkv_proj_kernel(
    const float* __restrict__ q,
    const float* __restrict__ k,
    const float* __restrict__ v,
    const float* __restrict__ Wqkv,
    const float* __restrict__ bqkv,
    float* __restrict__ ws)
{
  __shared__ __align__(16) float As[16][64];  // [k][m]
  __shared__ __align__(16) float Bs[16][64];  // [k][n]
  const int t = threadIdx.x;
  const int m0 = blockIdx.x * 64;
  const int n0g = blockIdx.y * 64;           // global col in [0, 3072)
  const int proj = n0g >> 10;                // /E
  const int nloc = n0g & (E_ - 1);
  const float* X = (proj == 0) ? q : (proj == 1) ? k : v;
  const int tx = t & 15, ty = t >> 4;
  const int lr = t >> 2;                     // tile row 0..63
  const int lk = (t & 3) * 4;                // k offset 0..12
  float acc[4][4] = {};

  for (int k0 = 0; k0 < E_; k0 += 16) {
    {
      const float4 ua = *(const float4*)(X + (size_t)(m0 + lr) * E_ + k0 + lk);
      As[lk + 0][lr] = ua.x; As[lk + 1][lr] = ua.y;
      As[lk + 2][lr] = ua.z; As[lk + 3][lr] = ua.w;
      const float4 uw = *(const float4*)(Wqkv + (size_t)(n0g + lr) * E_ + k0 + lk);
      Bs[lk + 0][lr] = uw.x; Bs[lk + 1][lr] = uw.y;
      Bs[lk + 2][lr] = uw.z; Bs[lk + 3][lr] = uw.w;
    }
    __syncthreads();
#pragma unroll
    for (int kk = 0; kk < 16; ++kk) {
      const float4 a = *(const float4*)&As[kk][ty * 4];
      const float4 b = *(const float4*)&Bs[kk][tx * 4];
      acc[0][0] += a.x * b.x; acc[0][1] += a.x * b.y; acc[0][2] += a.x * b.z; acc[0][3] += a.x * b.w;
      acc[1][0] += a.y * b.x; acc[1][1] += a.y * b.y; acc[1][2] += a.y * b.z; acc[1][3] += a.y * b.w;
      acc[2][0] += a.z * b.x; acc[2][1] += a.z * b.y; acc[2][2] += a.z * b.z; acc[2][3] += a.z * b.w;
      acc[3][0] += a.w * b.x; acc[3][1] += a.w * b.y; acc[3][2] += a.w * b.z; acc[3][3] += a.w * b.w;
    }
    __syncthreads();
  }

  const int h = nloc >> 6;                   // D = 64
  const int nc = tx * 4;
  const float b0 = bqkv[n0g + nc + 0];
  const float b1 = bqkv[n0g + nc + 1];
  const float b2 = bqkv[n0g + nc + 2];
  const float b3 = bqkv[n0g + nc + 3];
  float* dst = ws + (size_t)proj * ME_;
#pragma unroll
  for (int i = 0; i < 4; ++i) {
    const int m = m0 + ty * 4 + i;
    const int bb = m >> 11;                  // /S
    const int s = m & (S_ - 1);
    float4 o = make_float4(acc[i][0] + b0, acc[i][1] + b1, acc[i][2] + b2, acc[i][3] + b3);
    *(float4*)&dst[(((size_t)bb * H_ + h) * S_ + s) * D_ + nc] = o;
  }
}

// ---------------------------------------------------------------------------
// Kernel 2: flash-style attention, v2.
//  - K and V both staged row-major with b128 writes (no transpose -> no 8-way
//    scalar-store conflicts).
//  - Phase 1: thread owns key kc (t&63) for 4 q-rows (wave id).
//  - Phase 2: fully parallel online softmax (all 256 threads, shfl_xor over
//    the 16-lane group that shares a q-row).
//  - Phase 3: thread owns (q-row t>>4, 4 d-cols (t&15)*4); Sc read as
//    4-address-broadcast b128, Vs read as 16-granule b128 (~2-way, free).
// ---------------------------------------------------------------------------
__global__ __launch_bounds__(256) void attn_kernel(
    const float* __restrict__ ws,
    const int* __restrict__ mask,
    float* __restrict__ AO)
{
  const float* Qp = ws;
  const float* Kp = ws + ME_;
  const float* Vp = ws + 2 * ME_;

  __shared__ __align__(16) float Qs[16][64];
  __shared__ __align__(16) float Ks[64][68];  // [k][d], stride 68 (17 quads, odd)
  __shared__ __align__(16) float Vs[64][68];  // [k][d], row-major
  __shared__ __align__(16) float Sc[16][68];  // scores / probs
  __shared__ float m_sh[16], l_sh[16], al_sh[16];

  const int t = threadIdx.x;
  const int bh = blockIdx.y;                 // 0..31
  const int b = bh >> 4, hh = bh & (H_ - 1);
  const int q0 = blockIdx.x * 16;
  const size_t hb = (size_t)bh * S_ * D_;

  // stage Q tile (16x64 fp32, 1 float4/thread)
  {
    const int qr = t >> 4, dc = (t & 15) * 4;
    *(float4*)&Qs[qr][dc] = *(const float4*)&Qp[hb + (size_t)(q0 + qr) * D_ + dc];
  }
  if (t < 16) { m_sh[t] = -INFINITY; l_sh[t] = 0.f; }

  const int kc = t & 63;                     // phase-1 key ownership
  const int qg = t >> 6;                     // wave id (phase-1 q-group)
  const int pq = t >> 4;                     // phase-2/3 q-row (0..15)
  const int sub = t & 15;                    // 16-lane-group index
  const int d4 = sub * 4;                    // phase-3 d-columns

  float acc[4] = {0.f, 0.f, 0.f, 0.f};       // O accumulator: q-row pq, d4..d4+3

  for (int kt = 0; kt < S_; kt += 64) {
    __syncthreads();  // protect Ks/Vs/Sc from previous-iteration readers
    // stage K and V tiles, row-major, b128 (coalesced: 16 lanes = one 256B row)
#pragma unroll
    for (int r = 0; r < 4; ++r) {
      const int e = t + 256 * r;
      const int kr = e >> 4, ds = (e & 15) * 4;
      *(float4*)&Ks[kr][ds] = *(const float4*)&Kp[hb + (size_t)(kt + kr) * D_ + ds];
      *(float4*)&Vs[kr][ds] = *(const float4*)&Vp[hb + (size_t)(kt + kr) * D_ + ds];
    }
    __syncthreads();

    // phase 1: scores for 4 q-rows at key kc
    {
      float s0 = 0.f, s1 = 0.f, s2 = 0.f, s3 = 0.f;
#pragma unroll
      for (int d = 0; d < 64; d += 4) {
        const float4 kf = *(const float4*)&Ks[kc][d];
        const float4 qa = *(const float4*)&Qs[qg * 4 + 0][d];
        const float4 qb = *(const float4*)&Qs[qg * 4 + 1][d];
        const float4 qc = *(const float4*)&Qs[qg * 4 + 2][d];
        const float4 qd = *(const float4*)&Qs[qg * 4 + 3][d];
        s0 += qa.x * kf.x + qa.y * kf.y + qa.z * kf.z + qa.w * kf.w;
        s1 += qb.x * kf.x + qb.y * kf.y + qb.z * kf.z + qb.w * kf.w;
        s2 += qc.x * kf.x + qc.y * kf.y + qc.z * kf.z + qc.w * kf.w;
        s3 += qd.x * kf.x + qd.y * kf.y + qd.z * kf.z + qd.w * kf.w;
      }
      const bool msk = (mask[b * S_ + kt + kc] == 0);
      Sc[qg * 4 + 0][kc] = msk ? -1e20f : s0;
      Sc[qg * 4 + 1][kc] = msk ? -1e20f : s1;
      Sc[qg * 4 + 2][kc] = msk ? -1e20f : s2;
      Sc[qg * 4 + 3][kc] = msk ? -1e20f : s3;
    }
    __syncthreads();

    // phase 2: parallel online softmax. thread (pq, sub) owns Sc[pq][d4..d4+3].
    {
      float4 sv = *(const float4*)&Sc[pq][d4];
      float mx = fmaxf(fmaxf(sv.x, sv.y), fmaxf(sv.z, sv.w));
#pragma unroll
      for (int moff = 1; moff < 16; moff <<= 1)
        mx = fmaxf(mx, __shfl_xor(mx, moff, 64));
      const float mo = m_sh[pq];               // read BEFORE lane-0 write (lockstep)
      const float mn = fmaxf(mo, mx);
      float4 pv;
      pv.x = __expf(sv.x - mn); pv.y = __expf(sv.y - mn);
      pv.z = __expf(sv.z - mn); pv.w = __expf(sv.w - mn);
      float sum = pv.x + pv.y + pv.z + pv.w;
#pragma unroll
      for (int moff = 1; moff < 16; moff <<= 1)
        sum += __shfl_xor(sum, moff, 64);
      *(float4*)&Sc[pq][d4] = pv;
      if (sub == 0) {
        const float al = __expf(mo - mn);      // first tile: exp(-inf)=0
        m_sh[pq] = mn;
        l_sh[pq] = l_sh[pq] * al + sum;
        al_sh[pq] = al;
      }
    }
    __syncthreads();

    // phase 3: O rescale + PV. thread (pq, d4): 4 d-cols, all 64 keys.
    {
      const float al = al_sh[pq];
      acc[0] *= al; acc[1] *= al; acc[2] *= al; acc[3] *= al;
#pragma unroll
      for (int k4 = 0; k4 < 64; k4 += 4) {
        const float4 p  = *(const float4*)&Sc[pq][k4];
        const float4 v0 = *(const float4*)&Vs[k4 + 0][d4];
        const float4 v1 = *(const float4*)&Vs[k4 + 1][d4];
        const float4 v2 = *(const float4*)&Vs[k4 + 2][d4];
        const float4 v3 = *(const float4*)&Vs[k4 + 3][d4];
        acc[0] += p.x * v0.x + p.y * v1.x + p.z * v2.x + p.w * v3.x;
        acc[1] += p.x * v0.y + p.y * v1.y + p.z * v2.y + p.w * v3.y;
        acc[2] += p.x * v0.z + p.y * v1.z + p.z * v2.z + p.w * v3.z;
        acc[3] += p.x * v0.w + p.y * v1.w + p.z * v2.w + p.w * v3.w;
      }
    }
  }

  // epilogue: normalize and write [B,S,E] fp32 (float4, coalesced per 16 lanes)
  {
    const float linv = 1.0f / l_sh[pq];
    float4 o = make_float4(acc[0] * linv, acc[1] * linv, acc[2] * linv, acc[3] * linv);
    *(float4*)&AO[((size_t)(b * S_ + q0 + pq)) * E_ + hh * D_ + d4] = o;
  }
}

// ---------------------------------------------------------------------------
// Kernel 3: output projection. out[m][n] = sum_k AO[m][k]*W_out[n][k] + b_out[n]
// ---------------------------------------------------------------------------
__global__ __launch_bounds__(256) void out_proj_kernel(
    const float* __restrict__ AO,
    const float* __restrict__ Wout,
    const float* __restrict__ bout,
    float* __restrict__ out)
{
  __shared__ __align__(16) float As[16][64];
  __shared__ __align__(16) float Bs[16][64];
  const int t = threadIdx.x;
  const int m0 = blockIdx.x * 64;
  const int n0 = blockIdx.y * 64;
  const int tx = t & 15, ty = t >> 4;
  const int lr = t >> 2;
  const int lk = (t & 3) * 4;
  float acc[4][4] = {};

  for (int k0 = 0; k0 < E_; k0 += 16) {
    {
      const float4 la = *(const float4*)&AO[(size_t)(m0 + lr) * E_ + k0 + lk];
      As[lk + 0][lr] = la.x; As[lk + 1][lr] = la.y;
      As[lk + 2][lr] = la.z; As[lk + 3][lr] = la.w;
      const float4 uw = *(const float4*)(Wout + (size_t)(n0 + lr) * E_ + k0 + lk);
      Bs[lk + 0][lr] = uw.x; Bs[lk + 1][lr] = uw.y;
      Bs[lk + 2][lr] = uw.z; Bs[lk + 3][lr] = uw.w;
    }
    __syncthreads();
#pragma unroll
    for (int kk = 0; kk < 16; ++kk) {
      const float4 a = *(const float4*)&As[kk][ty * 4];
      const float4 b = *(const float4*)&Bs[kk][tx * 4];
      acc[0][0] += a.x * b.x; acc[0][1] += a.x * b.y; acc[0][2] += a.x * b.z; acc[0][3] += a.x * b.w;
      acc[1][0] += a.y * b.x; acc[1][1] += a.y * b.y; acc[1][2] += a.y * b.z; acc[1][3] += a.y * b.w;
      acc[2][0] += a.z * b.x; acc[2][1] += a.z * b.y; acc[2][2] += a.z * b.z; acc[2][3] += a.z * b.w;
      acc[3][0] += a.w * b.x; acc[3][1] += a.w * b.y; acc[3][2] += a.w * b.z; acc[3][3] += a.w * b.w;
    }
    __syncthreads();
  }

  const int nc = tx * 4;
  const float b0 = bout[n0 + nc + 0];
  const float b1 = bout[n0 + nc + 1];
  const float b2 = bout[n0 + nc + 2];
  const float b3 = bout[n0 + nc + 3];
#pragma unroll
  for (int i = 0; i < 4; ++i) {
    const int m = m0 + ty * 4 + i;
    float4 o = make_float4(acc[i][0] + b0, acc[i][1] + b1, acc[i][2] + b2, acc[i][3] + b3);
    *(float4*)&out[(size_t)m * E_ + n0 + nc] = o;
  }
}

// ---------------------------------------------------------------------------
extern "C" void kernel_launch(void* const* d_in, const int* in_sizes, int n_in,
                              void* d_out, int out_size, void* d_ws, size_t ws_size,
                              hipStream_t stream) {
  const float* q    = (const float*)d_in[0];
  const float* k    = (const float*)d_in[1];
  const float* v    = (const float*)d_in[2];
  const int*   mask = (const int*)d_in[3];
  const float* Wqkv = (const float*)d_in[4];
  const float* bqkv = (const float*)d_in[5];
  const float* Wout = (const float*)d_in[6];
  const float* bout = (const float*)d_in[7];

  float* ws = (float*)d_ws;           // [Qp | Kp | Vp | AO], each M_*E_ fp32
  float* AO = ws + 3 * ME_;
  float* out = (float*)d_out;

  hipLaunchKernelGGL(qkv_proj_kernel, dim3(M_ / 64, 48), dim3(256), 0, stream,
                     q, k, v, Wqkv, bqkv, ws);
  hipLaunchKernelGGL(attn_kernel, dim3(S_ / 16, B_ * H_), dim3(256), 0, stream,
                     ws, mask, AO);
  hipLaunchKernelGGL(out_proj_kernel, dim3(M_ / 64, E_ / 64), dim3(256), 0, stream,
                     AO, Wout, bout, out);
}

// Round 4
// 771.784 us; speedup vs baseline: 2.6442x; 1.9778x over previous
//
#include <hip/hip_runtime.h>
#include <stdint.h>

// Problem dims (fixed by the reference)
constexpr int B_ = 2, S_ = 2048, E_ = 1024, H_ = 16, D_ = 64;
constexpr int M_ = B_ * S_;              // 4096 rows
constexpr size_t ME_ = (size_t)M_ * E_;  // 4,194,304

typedef __attribute__((ext_vector_type(8))) short short8;
typedef __attribute__((ext_vector_type(4))) float f32x4;

__device__ __forceinline__ float bf2f(unsigned short u) {
  union { uint32_t i; float f; } v; v.i = ((uint32_t)u) << 16; return v.f;
}
__device__ __forceinline__ unsigned short f2bf(float f) {
  uint32_t u = __float_as_uint(f);
  uint32_t r = (u + 0x7FFFu + ((u >> 16) & 1u)) >> 16;  // RNE
  return (unsigned short)r;
}

// ---------------------------------------------------------------------------
// Kernel 1: fused QKV projection (fp32 VALU — unchanged this round).
// ---------------------------------------------------------------------------
__global__ __launch_bounds__(256) void qkv_proj_kernel(
    const float* __restrict__ q,
    const float* __restrict__ k,
    const float* __restrict__ v,
    const float* __restrict__ Wqkv,
    const float* __restrict__ bqkv,
    float* __restrict__ ws)
{
  __shared__ __align__(16) float As[16][64];  // [k][m]
  __shared__ __align__(16) float Bs[16][64];  // [k][n]
  const int t = threadIdx.x;
  const int m0 = blockIdx.x * 64;
  const int n0g = blockIdx.y * 64;           // global col in [0, 3072)
  const int proj = n0g >> 10;                // /E
  const int nloc = n0g & (E_ - 1);
  const float* X = (proj == 0) ? q : (proj == 1) ? k : v;
  const int tx = t & 15, ty = t >> 4;
  const int lr = t >> 2;                     // tile row 0..63
  const int lk = (t & 3) * 4;                // k offset 0..12
  float acc[4][4] = {};

  for (int k0 = 0; k0 < E_; k0 += 16) {
    {
      const float4 ua = *(const float4*)(X + (size_t)(m0 + lr) * E_ + k0 + lk);
      As[lk + 0][lr] = ua.x; As[lk + 1][lr] = ua.y;
      As[lk + 2][lr] = ua.z; As[lk + 3][lr] = ua.w;
      const float4 uw = *(const float4*)(Wqkv + (size_t)(n0g + lr) * E_ + k0 + lk);
      Bs[lk + 0][lr] = uw.x; Bs[lk + 1][lr] = uw.y;
      Bs[lk + 2][lr] = uw.z; Bs[lk + 3][lr] = uw.w;
    }
    __syncthreads();
#pragma unroll
    for (int kk = 0; kk < 16; ++kk) {
      const float4 a = *(const float4*)&As[kk][ty * 4];
      const float4 b = *(const float4*)&Bs[kk][tx * 4];
      acc[0][0] += a.x * b.x; acc[0][1] += a.x * b.y; acc[0][2] += a.x * b.z; acc[0][3] += a.x * b.w;
      acc[1][0] += a.y * b.x; acc[1][1] += a.y * b.y; acc[1][2] += a.y * b.z; acc[1][3] += a.y * b.w;
      acc[2][0] += a.z * b.x; acc[2][1] += a.z * b.y; acc[2][2] += a.z * b.z; acc[2][3] += a.z * b.w;
      acc[3][0] += a.w * b.x; acc[3][1] += a.w * b.y; acc[3][2] += a.w * b.z; acc[3][3] += a.w * b.w;
    }
    __syncthreads();
  }

  const int h = nloc >> 6;                   // D = 64
  const int nc = tx * 4;
  const float b0 = bqkv[n0g + nc + 0];
  const float b1 = bqkv[n0g + nc + 1];
  const float b2 = bqkv[n0g + nc + 2];
  const float b3 = bqkv[n0g + nc + 3];
  float* dst = ws + (size_t)proj * ME_;
#pragma unroll
  for (int i = 0; i < 4; ++i) {
    const int m = m0 + ty * 4 + i;
    const int bb = m >> 11;                  // /S
    const int s = m & (S_ - 1);
    float4 o = make_float4(acc[i][0] + b0, acc[i][1] + b1, acc[i][2] + b2, acc[i][3] + b3);
    *(float4*)&dst[(((size_t)bb * H_ + h) * S_ + s) * D_ + nc] = o;
  }
}

// ---------------------------------------------------------------------------
// Kernel 2: MFMA flash attention.
//  Block = 256 (4 waves), 64 q-rows/block (16 per wave), one (b,h) per blk.y.
//  QK^T: split-bf16 (hi/lo) -> 6 mfma_16x16x32 per 16-key tile, fp32 C.
//  Softmax in registers (C layout: col=lane&15=key, row=(lane>>4)*4+reg=q).
//  P -> bf16 LDS (C->A layout round trip), PV: 8 mfma per 64-key tile.
//  K LDS [key][d] stride 72, Vt LDS [d][key] stride 72 (bank-balanced b128).
// ---------------------------------------------------------------------------
__global__ __launch_bounds__(256) void attn_mfma_kernel(
    const float* __restrict__ ws,
    const int* __restrict__ mask,
    float* __restrict__ AO)
{
  __shared__ short sm[18432];                // 36,864 B
  short* Khi = sm;                           // [64][72]
  short* Klo = sm + 4608;                    // [64][72]
  short* Vt  = sm + 9216;                    // [64][72] (d-major)
  short* Pb  = sm + 13824;                   // 4 x [16][72]

  const int t = threadIdx.x;
  const int w = t >> 6, lane = t & 63;
  const int g_ = lane >> 4, m = lane & 15;
  const int bh = blockIdx.y;
  const int b = bh >> 4, hh = bh & 15;
  const int q0 = blockIdx.x * 64;
  const size_t hb = (size_t)bh * S_ * D_;
  const float* Qp = ws + hb;
  const float* Kp = ws + ME_ + hb;
  const float* Vp = ws + 2 * ME_ + hb;
  short* Pw = Pb + w * (16 * 72);

  // ---- prologue: stage Q tile (64x64) hi/lo into K buffers, load A-frags ----
  {
    const float* Qg = Qp + (size_t)q0 * D_;
#pragma unroll
    for (int r = 0; r < 4; ++r) {
      const int row = (t >> 4) + 16 * r;
      const int c4 = (t & 15) * 4;
      const float4 x = *(const float4*)&Qg[row * 64 + c4];
      ushort4 hi, lo;
      hi.x = f2bf(x.x); lo.x = f2bf(x.x - bf2f(hi.x));
      hi.y = f2bf(x.y); lo.y = f2bf(x.y - bf2f(hi.y));
      hi.z = f2bf(x.z); lo.z = f2bf(x.z - bf2f(hi.z));
      hi.w = f2bf(x.w); lo.w = f2bf(x.w - bf2f(hi.w));
      *(ushort4*)&Khi[row * 72 + c4] = hi;
      *(ushort4*)&Klo[row * 72 + c4] = lo;
    }
  }
  __syncthreads();
  short8 qh0, qh1, ql0, ql1;
  {
    const int ro = (16 * w + m) * 72 + 8 * g_;
    qh0 = *(const short8*)&Khi[ro];
    qh1 = *(const short8*)&Khi[ro + 32];
    ql0 = *(const short8*)&Klo[ro];
    ql1 = *(const short8*)&Klo[ro + 32];
  }

  f32x4 O0 = {0,0,0,0}, O1 = {0,0,0,0}, O2 = {0,0,0,0}, O3 = {0,0,0,0};
  float mstate[4] = {-INFINITY, -INFINITY, -INFINITY, -INFINITY};
  float lstate[4] = {0.f, 0.f, 0.f, 0.f};

  for (int kt = 0; kt < S_; kt += 64) {
    __syncthreads();                         // previous tile fully consumed
    // ---- stage K (hi/lo, [key][d]) and V (transposed bf16 [d][key]) ----
    {
      const float* Kg = Kp + (size_t)kt * D_;
#pragma unroll
      for (int r = 0; r < 4; ++r) {
        const int row = (t >> 4) + 16 * r;
        const int c4 = (t & 15) * 4;
        const float4 x = *(const float4*)&Kg[row * 64 + c4];
        ushort4 hi, lo;
        hi.x = f2bf(x.x); lo.x = f2bf(x.x - bf2f(hi.x));
        hi.y = f2bf(x.y); lo.y = f2bf(x.y - bf2f(hi.y));
        hi.z = f2bf(x.z); lo.z = f2bf(x.z - bf2f(hi.z));
        hi.w = f2bf(x.w); lo.w = f2bf(x.w - bf2f(hi.w));
        *(ushort4*)&Khi[row * 72 + c4] = hi;
        *(ushort4*)&Klo[row * 72 + c4] = lo;
      }
      const float* Vg = Vp + (size_t)kt * D_;
      const int d = t & 63, kg = t >> 6;
#pragma unroll
      for (int r = 0; r < 4; ++r) {
        const int kb = 16 * r + 4 * ((kg + d) & 3);   // bank stagger
        ushort4 u;
        u.x = f2bf(Vg[(kb + 0) * 64 + d]);
        u.y = f2bf(Vg[(kb + 1) * 64 + d]);
        u.z = f2bf(Vg[(kb + 2) * 64 + d]);
        u.w = f2bf(Vg[(kb + 3) * 64 + d]);
        *(ushort4*)&Vt[d * 72 + kb] = u;
      }
    }
    __syncthreads();

    // ---- scores: S[16q x 64k] via split-bf16 MFMA ----
    f32x4 sc[4];
#pragma unroll
    for (int kt16 = 0; kt16 < 4; ++kt16) {
      const int ko = (16 * kt16 + m) * 72 + 8 * g_;
      const short8 kh0 = *(const short8*)&Khi[ko];
      const short8 kh1 = *(const short8*)&Khi[ko + 32];
      const short8 kl0 = *(const short8*)&Klo[ko];
      const short8 kl1 = *(const short8*)&Klo[ko + 32];
      f32x4 a = {0,0,0,0};
      a = __builtin_amdgcn_mfma_f32_16x16x32_bf16(qh0, kh0, a, 0, 0, 0);
      a = __builtin_amdgcn_mfma_f32_16x16x32_bf16(qh1, kh1, a, 0, 0, 0);
      a = __builtin_amdgcn_mfma_f32_16x16x32_bf16(qh0, kl0, a, 0, 0, 0);
      a = __builtin_amdgcn_mfma_f32_16x16x32_bf16(qh1, kl1, a, 0, 0, 0);
      a = __builtin_amdgcn_mfma_f32_16x16x32_bf16(ql0, kh0, a, 0, 0, 0);
      a = __builtin_amdgcn_mfma_f32_16x16x32_bf16(ql1, kh1, a, 0, 0, 0);
      sc[kt16] = a;
    }

    // ---- mask (key col = 16*kt16 + m) ----
#pragma unroll
    for (int kt16 = 0; kt16 < 4; ++kt16) {
      if (mask[b * S_ + kt + 16 * kt16 + m] == 0) {
        sc[kt16][0] = -1e20f; sc[kt16][1] = -1e20f;
        sc[kt16][2] = -1e20f; sc[kt16][3] = -1e20f;
      }
    }

    // ---- online softmax (per wave, butterfly over the 16-lane col group) ----
    float al[4];
#pragma unroll
    for (int r = 0; r < 4; ++r) {
      float v = fmaxf(fmaxf(sc[0][r], sc[1][r]), fmaxf(sc[2][r], sc[3][r]));
      v = fmaxf(v, __shfl_xor(v, 1));
      v = fmaxf(v, __shfl_xor(v, 2));
      v = fmaxf(v, __shfl_xor(v, 4));
      v = fmaxf(v, __shfl_xor(v, 8));
      const float mn = fmaxf(mstate[r], v);
      al[r] = __expf(mstate[r] - mn);        // first tile: exp(-inf)=0
      mstate[r] = mn;
    }
    float rs[4] = {0.f, 0.f, 0.f, 0.f};
#pragma unroll
    for (int kt16 = 0; kt16 < 4; ++kt16) {
#pragma unroll
      for (int r = 0; r < 4; ++r) {
        const float p = __expf(sc[kt16][r] - mstate[r]);
        sc[kt16][r] = p;
        rs[r] += p;
      }
    }
#pragma unroll
    for (int r = 0; r < 4; ++r) {
      rs[r] += __shfl_xor(rs[r], 1);
      rs[r] += __shfl_xor(rs[r], 2);
      rs[r] += __shfl_xor(rs[r], 4);
      rs[r] += __shfl_xor(rs[r], 8);
      lstate[r] = lstate[r] * al[r] + rs[r];
    }
    const f32x4 alv = {al[0], al[1], al[2], al[3]};
    O0 *= alv; O1 *= alv; O2 *= alv; O3 *= alv;

    // ---- P: C-layout regs -> bf16 LDS (A-layout source for PV) ----
#pragma unroll
    for (int kt16 = 0; kt16 < 4; ++kt16) {
#pragma unroll
      for (int r = 0; r < 4; ++r)
        Pw[(4 * g_ + r) * 72 + 16 * kt16 + m] = (short)f2bf(sc[kt16][r]);
    }

    // ---- PV: O += P(16x64) * V(64x64) ----
    {
      const short8 pa0 = *(const short8*)&Pw[m * 72 + 8 * g_];
      const short8 pa1 = *(const short8*)&Pw[m * 72 + 32 + 8 * g_];
#pragma unroll
      for (int dt = 0; dt < 4; ++dt) {
        const int vo = (16 * dt + m) * 72 + 8 * g_;
        const short8 vb0 = *(const short8*)&Vt[vo];
        const short8 vb1 = *(const short8*)&Vt[vo + 32];
        f32x4 o = (dt == 0) ? O0 : (dt == 1) ? O1 : (dt == 2) ? O2 : O3;
        o = __builtin_amdgcn_mfma_f32_16x16x32_bf16(pa0, vb0, o, 0, 0, 0);
        o = __builtin_amdgcn_mfma_f32_16x16x32_bf16(pa1, vb1, o, 0, 0, 0);
        if (dt == 0) O0 = o; else if (dt == 1) O1 = o; else if (dt == 2) O2 = o; else O3 = o;
      }
    }
  }

  // ---- epilogue: normalize, write AO [B,S,E] fp32 ----
  {
    const f32x4 li = {1.f / lstate[0], 1.f / lstate[1], 1.f / lstate[2], 1.f / lstate[3]};
    O0 *= li; O1 *= li; O2 *= li; O3 *= li;
#pragma unroll
    for (int r = 0; r < 4; ++r) {
      const size_t rowb = (size_t)(b * S_ + q0 + 16 * w + 4 * g_ + r) * E_ + hh * 64;
      AO[rowb + m]      = O0[r];
      AO[rowb + 16 + m] = O1[r];
      AO[rowb + 32 + m] = O2[r];
      AO[rowb + 48 + m] = O3[r];
    }
  }
}

// ---------------------------------------------------------------------------
// Kernel 3: output projection (fp32 VALU — unchanged this round).
// ---------------------------------------------------------------------------
__global__ __launch_bounds__(256) void out_proj_kernel(
    const float* __restrict__ AO,
    const float* __restrict__ Wout,
    const float* __restrict__ bout,
    float* __restrict__ out)
{
  __shared__ __align__(16) float As[16][64];
  __shared__ __align__(16) float Bs[16][64];
  const int t = threadIdx.x;
  const int m0 = blockIdx.x * 64;
  const int n0 = blockIdx.y * 64;
  const int tx = t & 15, ty = t >> 4;
  const int lr = t >> 2;
  const int lk = (t & 3) * 4;
  float acc[4][4] = {};

  for (int k0 = 0; k0 < E_; k0 += 16) {
    {
      const float4 la = *(const float4*)&AO[(size_t)(m0 + lr) * E_ + k0 + lk];
      As[lk + 0][lr] = la.x; As[lk + 1][lr] = la.y;
      As[lk + 2][lr] = la.z; As[lk + 3][lr] = la.w;
      const float4 uw = *(const float4*)(Wout + (size_t)(n0 + lr) * E_ + k0 + lk);
      Bs[lk + 0][lr] = uw.x; Bs[lk + 1][lr] = uw.y;
      Bs[lk + 2][lr] = uw.z; Bs[lk + 3][lr] = uw.w;
    }
    __syncthreads();
#pragma unroll
    for (int kk = 0; kk < 16; ++kk) {
      const float4 a = *(const float4*)&As[kk][ty * 4];
      const float4 b = *(const float4*)&Bs[kk][tx * 4];
      acc[0][0] += a.x * b.x; acc[0][1] += a.x * b.y; acc[0][2] += a.x * b.z; acc[0][3] += a.x * b.w;
      acc[1][0] += a.y * b.x; acc[1][1] += a.y * b.y; acc[1][2] += a.y * b.z; acc[1][3] += a.y * b.w;
      acc[2][0] += a.z * b.x; acc[2][1] += a.z * b.y; acc[2][2] += a.z * b.z; acc[2][3] += a.z * b.w;
      acc[3][0] += a.w * b.x; acc[3][1] += a.w * b.y; acc[3][2] += a.w * b.z; acc[3][3] += a.w * b.w;
    }
    __syncthreads();
  }

  const int nc = tx * 4;
  const float b0 = bout[n0 + nc + 0];
  const float b1 = bout[n0 + nc + 1];
  const float b2 = bout[n0 + nc + 2];
  const float b3 = bout[n0 + nc + 3];
#pragma unroll
  for (int i = 0; i < 4; ++i) {
    const int m = m0 + ty * 4 + i;
    float4 o = make_float4(acc[i][0] + b0, acc[i][1] + b1, acc[i][2] + b2, acc[i][3] + b3);
    *(float4*)&out[(size_t)m * E_ + n0 + nc] = o;
  }
}

// ---------------------------------------------------------------------------
extern "C" void kernel_launch(void* const* d_in, const int* in_sizes, int n_in,
                              void* d_out, int out_size, void* d_ws, size_t ws_size,
                              hipStream_t stream) {
  const float* q    = (const float*)d_in[0];
  const float* k    = (const float*)d_in[1];
  const float* v    = (const float*)d_in[2];
  const int*   mask = (const int*)d_in[3];
  const float* Wqkv = (const float*)d_in[4];
  const float* bqkv = (const float*)d_in[5];
  const float* Wout = (const float*)d_in[6];
  const float* bout = (const float*)d_in[7];

  float* ws = (float*)d_ws;           // [Qp | Kp | Vp | AO], each M_*E_ fp32
  float* AO = ws + 3 * ME_;
  float* out = (float*)d_out;

  hipLaunchKernelGGL(qkv_proj_kernel, dim3(M_ / 64, 48), dim3(256), 0, stream,
                     q, k, v, Wqkv, bqkv, ws);
  hipLaunchKernelGGL(attn_mfma_kernel, dim3(S_ / 64, B_ * H_), dim3(256), 0, stream,
                     ws, mask, AO);
  hipLaunchKernelGGL(out_proj_kernel, dim3(M_ / 64, E_ / 64), dim3(256), 0, stream,
                     AO, Wout, bout, out);
}

// Round 5
// 422.999 us; speedup vs baseline: 4.8245x; 1.8246x over previous
//
#include <hip/hip_runtime.h>
#include <stdint.h>

// Problem dims (fixed by the reference)
constexpr int B_ = 2, S_ = 2048, E_ = 1024, H_ = 16, D_ = 64;
constexpr int M_ = B_ * S_;              // 4096 rows
constexpr size_t ME_ = (size_t)M_ * E_;  // 4,194,304

typedef unsigned short u16;
typedef __attribute__((ext_vector_type(8))) short short8;
typedef __attribute__((ext_vector_type(4))) float f32x4;

__device__ __forceinline__ float bf2f(u16 u) {
  union { uint32_t i; float f; } v; v.i = ((uint32_t)u) << 16; return v.f;
}
__device__ __forceinline__ u16 f2bf(float f) {
  uint32_t u = __float_as_uint(f);
  return (u16)((u + 0x7FFFu + ((u >> 16) & 1u)) >> 16);  // RNE
}

// ---------------------------------------------------------------------------
// Kernel 0: split fp32 -> (hi, lo) bf16 pair, elementwise (weights).
// ---------------------------------------------------------------------------
__global__ __launch_bounds__(256) void split_f32_kernel(
    const float* __restrict__ src, u16* __restrict__ hi, u16* __restrict__ lo, int n4)
{
  const int i = blockIdx.x * 256 + threadIdx.x;
  if (i >= n4) return;
  const float4 x = ((const float4*)src)[i];
  ushort4 h, l;
  h.x = f2bf(x.x); l.x = f2bf(x.x - bf2f(h.x));
  h.y = f2bf(x.y); l.y = f2bf(x.y - bf2f(h.y));
  h.z = f2bf(x.z); l.z = f2bf(x.z - bf2f(h.z));
  h.w = f2bf(x.w); l.w = f2bf(x.w - bf2f(h.w));
  ((ushort4*)hi)[i] = h;
  ((ushort4*)lo)[i] = l;
}

// ---------------------------------------------------------------------------
// Kernel 1: QKV projection, split-bf16 MFMA.
// 128x128 tile / block, 4 waves (2x2), each wave 64x64 = 4x4 mfma 16x16x32.
// A = q/k/v fp32 (converted hi/lo during staging); B = pre-split W_qkv.
// Epilogue: Q,K -> hi/lo bf16 [B,H,S,D]; V -> bf16 [B,H,D,S] (pre-transposed).
// ---------------------------------------------------------------------------
__global__ __launch_bounds__(256) void gemm_qkv_kernel(
    const float* __restrict__ q, const float* __restrict__ k, const float* __restrict__ v,
    const u16* __restrict__ WHi, const u16* __restrict__ WLo,
    const float* __restrict__ bias,
    u16* __restrict__ QpHi, u16* __restrict__ QpLo,
    u16* __restrict__ KpHi, u16* __restrict__ KpLo,
    u16* __restrict__ Vp)
{
  __shared__ __align__(16) short Ah[128 * 40], Al[128 * 40];
  __shared__ __align__(16) short Bh[128 * 40], Bl[128 * 40];

  const int t = threadIdx.x;
  const int m0 = blockIdx.x * 128;
  const int n0g = blockIdx.y * 128;          // global col in [0, 3072)
  const int proj = n0g >> 10;
  const int nloc = n0g & (E_ - 1);
  const float* A = (proj == 0) ? q : (proj == 1) ? k : v;

  const int w = t >> 6, lane = t & 63;
  const int g = lane >> 4, lc = lane & 15;
  const int wm = w & 1, wn = w >> 1;
  const int srow = t >> 1, sh = (t & 1) * 16; // staging: 2 threads/row, 16 elems each

  const float* Ab = A + (size_t)(m0 + srow) * E_ + sh;
  const u16* Bhb = WHi + (size_t)(n0g + srow) * E_ + sh;
  const u16* Blb = WLo + (size_t)(n0g + srow) * E_ + sh;

  f32x4 acc[4][4];
#pragma unroll
  for (int i = 0; i < 4; ++i)
#pragma unroll
    for (int j = 0; j < 4; ++j) acc[i][j] = (f32x4){0.f, 0.f, 0.f, 0.f};

  for (int k0 = 0; k0 < E_; k0 += 32) {
    __syncthreads();
    // stage A: fp32 -> hi/lo bf16
#pragma unroll
    for (int i = 0; i < 4; ++i) {
      const float4 x = *(const float4*)(Ab + k0 + 4 * i);
      ushort4 h, l;
      h.x = f2bf(x.x); l.x = f2bf(x.x - bf2f(h.x));
      h.y = f2bf(x.y); l.y = f2bf(x.y - bf2f(h.y));
      h.z = f2bf(x.z); l.z = f2bf(x.z - bf2f(h.z));
      h.w = f2bf(x.w); l.w = f2bf(x.w - bf2f(h.w));
      *(ushort4*)&Ah[srow * 40 + sh + 4 * i] = h;
      *(ushort4*)&Al[srow * 40 + sh + 4 * i] = l;
    }
    // stage B: straight bf16 copy
    {
      const short8 b0 = *(const short8*)(Bhb + k0);
      const short8 b1 = *(const short8*)(Bhb + k0 + 8);
      *(short8*)&Bh[srow * 40 + sh] = b0;
      *(short8*)&Bh[srow * 40 + sh + 8] = b1;
      const short8 c0 = *(const short8*)(Blb + k0);
      const short8 c1 = *(const short8*)(Blb + k0 + 8);
      *(short8*)&Bl[srow * 40 + sh] = c0;
      *(short8*)&Bl[srow * 40 + sh + 8] = c1;
    }
    __syncthreads();

    short8 ah[4], al[4], bh[4], bl[4];
#pragma unroll
    for (int mt = 0; mt < 4; ++mt) {
      const int ro = (wm * 64 + mt * 16 + lc) * 40 + g * 8;
      ah[mt] = *(const short8*)&Ah[ro];
      al[mt] = *(const short8*)&Al[ro];
    }
#pragma unroll
    for (int nt = 0; nt < 4; ++nt) {
      const int ro = (wn * 64 + nt * 16 + lc) * 40 + g * 8;
      bh[nt] = *(const short8*)&Bh[ro];
      bl[nt] = *(const short8*)&Bl[ro];
    }
#pragma unroll
    for (int mt = 0; mt < 4; ++mt)
#pragma unroll
      for (int nt = 0; nt < 4; ++nt) {
        f32x4 a = acc[mt][nt];
        a = __builtin_amdgcn_mfma_f32_16x16x32_bf16(ah[mt], bh[nt], a, 0, 0, 0);
        a = __builtin_amdgcn_mfma_f32_16x16x32_bf16(ah[mt], bl[nt], a, 0, 0, 0);
        a = __builtin_amdgcn_mfma_f32_16x16x32_bf16(al[mt], bh[nt], a, 0, 0, 0);
        acc[mt][nt] = a;
      }
  }

  // epilogue
  float bs[4];
#pragma unroll
  for (int nt = 0; nt < 4; ++nt) bs[nt] = bias[n0g + wn * 64 + nt * 16 + lc];

  if (proj < 2) {
    u16* Hi = (proj == 0) ? QpHi : KpHi;
    u16* Lo = (proj == 0) ? QpLo : KpLo;
#pragma unroll
    for (int nt = 0; nt < 4; ++nt) {
      const int nE = nloc + wn * 64 + nt * 16 + lc;
      const int h = nE >> 6, d = nE & 63;
#pragma unroll
      for (int mt = 0; mt < 4; ++mt) {
#pragma unroll
        for (int r = 0; r < 4; ++r) {
          const int mrow = m0 + wm * 64 + mt * 16 + g * 4 + r;
          const int bb = mrow >> 11, s = mrow & (S_ - 1);
          const float val = acc[mt][nt][r] + bs[nt];
          const u16 h16 = f2bf(val);
          const size_t addr = (((size_t)(bb * H_ + h)) * S_ + s) * D_ + d;
          Hi[addr] = h16;
          Lo[addr] = f2bf(val - bf2f(h16));
        }
      }
    }
  } else {
#pragma unroll
    for (int nt = 0; nt < 4; ++nt) {
      const int nE = nloc + wn * 64 + nt * 16 + lc;
      const int h = nE >> 6, d = nE & 63;
#pragma unroll
      for (int mt = 0; mt < 4; ++mt) {
        const int mrow = m0 + wm * 64 + mt * 16 + g * 4;
        const int bb = mrow >> 11, s = mrow & (S_ - 1);
        ushort4 u;
        u.x = f2bf(acc[mt][nt][0] + bs[nt]);
        u.y = f2bf(acc[mt][nt][1] + bs[nt]);
        u.z = f2bf(acc[mt][nt][2] + bs[nt]);
        u.w = f2bf(acc[mt][nt][3] + bs[nt]);
        *(ushort4*)&Vp[(((size_t)(bb * H_ + h)) * D_ + d) * S_ + s] = u;
      }
    }
  }
}

// ---------------------------------------------------------------------------
// Kernel 2: MFMA flash attention (consumes pre-split bf16 Q/K, transposed V).
// ---------------------------------------------------------------------------
__global__ __launch_bounds__(256) void attn_mfma_kernel(
    const u16* __restrict__ QpHi, const u16* __restrict__ QpLo,
    const u16* __restrict__ KpHi, const u16* __restrict__ KpLo,
    const u16* __restrict__ Vp,
    const int* __restrict__ mask,
    u16* __restrict__ AOHi, u16* __restrict__ AOLo)
{
  __shared__ __align__(16) short sm[18432];  // 36,864 B
  short* Khi = sm;                           // [64][72]
  short* Klo = sm + 4608;                    // [64][72]
  short* Vt  = sm + 9216;                    // [64][72] (d-major)
  short* Pb  = sm + 13824;                   // 4 x [16][72]

  const int t = threadIdx.x;
  const int w = t >> 6, lane = t & 63;
  const int g = lane >> 4, lc = lane & 15;
  const int bh = blockIdx.y;
  const int b = bh >> 4, hh = bh & 15;
  const int q0 = blockIdx.x * 64;
  const size_t hb = (size_t)bh * S_ * D_;    // 131072 elems per (b,h) for all of Qp/Kp/Vp
  const u16* QgH = QpHi + hb;
  const u16* QgL = QpLo + hb;
  const u16* KgH = KpHi + hb;
  const u16* KgL = KpLo + hb;
  const u16* Vg  = Vp + hb;
  short* Pw = Pb + w * (16 * 72);

  const int srow = t >> 2, sc16 = (t & 3) * 16;   // staging: 4 threads/row

  // ---- prologue: stage Q tile (64x64 hi/lo) into K buffers, extract frags ----
  {
    *(short8*)&Khi[srow * 72 + sc16]     = *(const short8*)&QgH[(q0 + srow) * D_ + sc16];
    *(short8*)&Khi[srow * 72 + sc16 + 8] = *(const short8*)&QgH[(q0 + srow) * D_ + sc16 + 8];
    *(short8*)&Klo[srow * 72 + sc16]     = *(const short8*)&QgL[(q0 + srow) * D_ + sc16];
    *(short8*)&Klo[srow * 72 + sc16 + 8] = *(const short8*)&QgL[(q0 + srow) * D_ + sc16 + 8];
  }
  __syncthreads();
  short8 qh0, qh1, ql0, ql1;
  {
    const int ro = (16 * w + lc) * 72 + 8 * g;
    qh0 = *(const short8*)&Khi[ro];
    qh1 = *(const short8*)&Khi[ro + 32];
    ql0 = *(const short8*)&Klo[ro];
    ql1 = *(const short8*)&Klo[ro + 32];
  }

  f32x4 O0 = {0,0,0,0}, O1 = {0,0,0,0}, O2 = {0,0,0,0}, O3 = {0,0,0,0};
  float mstate[4] = {-INFINITY, -INFINITY, -INFINITY, -INFINITY};
  float lstate[4] = {0.f, 0.f, 0.f, 0.f};

  for (int kt = 0; kt < S_; kt += 64) {
    __syncthreads();                         // previous tile fully consumed
    // ---- stage K hi/lo ([key][d]) and V ([d][key]) — pure bf16 copies ----
    *(short8*)&Khi[srow * 72 + sc16]     = *(const short8*)&KgH[(kt + srow) * D_ + sc16];
    *(short8*)&Khi[srow * 72 + sc16 + 8] = *(const short8*)&KgH[(kt + srow) * D_ + sc16 + 8];
    *(short8*)&Klo[srow * 72 + sc16]     = *(const short8*)&KgL[(kt + srow) * D_ + sc16];
    *(short8*)&Klo[srow * 72 + sc16 + 8] = *(const short8*)&KgL[(kt + srow) * D_ + sc16 + 8];
    *(short8*)&Vt[srow * 72 + sc16]      = *(const short8*)&Vg[srow * S_ + kt + sc16];
    *(short8*)&Vt[srow * 72 + sc16 + 8]  = *(const short8*)&Vg[srow * S_ + kt + sc16 + 8];
    __syncthreads();

    // ---- scores: S[16q x 64k] via split-bf16 MFMA ----
    f32x4 sc[4];
#pragma unroll
    for (int kt16 = 0; kt16 < 4; ++kt16) {
      const int ko = (16 * kt16 + lc) * 72 + 8 * g;
      const short8 kh0 = *(const short8*)&Khi[ko];
      const short8 kh1 = *(const short8*)&Khi[ko + 32];
      const short8 kl0 = *(const short8*)&Klo[ko];
      const short8 kl1 = *(const short8*)&Klo[ko + 32];
      f32x4 a = {0,0,0,0};
      a = __builtin_amdgcn_mfma_f32_16x16x32_bf16(qh0, kh0, a, 0, 0, 0);
      a = __builtin_amdgcn_mfma_f32_16x16x32_bf16(qh1, kh1, a, 0, 0, 0);
      a = __builtin_amdgcn_mfma_f32_16x16x32_bf16(qh0, kl0, a, 0, 0, 0);
      a = __builtin_amdgcn_mfma_f32_16x16x32_bf16(qh1, kl1, a, 0, 0, 0);
      a = __builtin_amdgcn_mfma_f32_16x16x32_bf16(ql0, kh0, a, 0, 0, 0);
      a = __builtin_amdgcn_mfma_f32_16x16x32_bf16(ql1, kh1, a, 0, 0, 0);
      sc[kt16] = a;
    }

    // ---- mask (key col = 16*kt16 + lc) ----
#pragma unroll
    for (int kt16 = 0; kt16 < 4; ++kt16) {
      if (mask[b * S_ + kt + 16 * kt16 + lc] == 0) {
        sc[kt16][0] = -1e20f; sc[kt16][1] = -1e20f;
        sc[kt16][2] = -1e20f; sc[kt16][3] = -1e20f;
      }
    }

    // ---- online softmax (per wave, butterfly over 16-lane col group) ----
    float al[4];
#pragma unroll
    for (int r = 0; r < 4; ++r) {
      float vv = fmaxf(fmaxf(sc[0][r], sc[1][r]), fmaxf(sc[2][r], sc[3][r]));
      vv = fmaxf(vv, __shfl_xor(vv, 1));
      vv = fmaxf(vv, __shfl_xor(vv, 2));
      vv = fmaxf(vv, __shfl_xor(vv, 4));
      vv = fmaxf(vv, __shfl_xor(vv, 8));
      const float mn = fmaxf(mstate[r], vv);
      al[r] = __expf(mstate[r] - mn);        // first tile: exp(-inf)=0
      mstate[r] = mn;
    }
    float rs[4] = {0.f, 0.f, 0.f, 0.f};
#pragma unroll
    for (int kt16 = 0; kt16 < 4; ++kt16) {
#pragma unroll
      for (int r = 0; r < 4; ++r) {
        const float p = __expf(sc[kt16][r] - mstate[r]);
        sc[kt16][r] = p;
        rs[r] += p;
      }
    }
#pragma unroll
    for (int r = 0; r < 4; ++r) {
      rs[r] += __shfl_xor(rs[r], 1);
      rs[r] += __shfl_xor(rs[r], 2);
      rs[r] += __shfl_xor(rs[r], 4);
      rs[r] += __shfl_xor(rs[r], 8);
      lstate[r] = lstate[r] * al[r] + rs[r];
    }
    const f32x4 alv = {al[0], al[1], al[2], al[3]};
    O0 *= alv; O1 *= alv; O2 *= alv; O3 *= alv;

    // ---- P: C-layout regs -> bf16 LDS (A-layout source for PV) ----
#pragma unroll
    for (int kt16 = 0; kt16 < 4; ++kt16) {
#pragma unroll
      for (int r = 0; r < 4; ++r)
        Pw[(4 * g + r) * 72 + 16 * kt16 + lc] = (short)f2bf(sc[kt16][r]);
    }

    // ---- PV: O += P(16x64) * V(64x64) ----
    {
      const short8 pa0 = *(const short8*)&Pw[lc * 72 + 8 * g];
      const short8 pa1 = *(const short8*)&Pw[lc * 72 + 32 + 8 * g];
#pragma unroll
      for (int dt = 0; dt < 4; ++dt) {
        const int vo = (16 * dt + lc) * 72 + 8 * g;
        const short8 vb0 = *(const short8*)&Vt[vo];
        const short8 vb1 = *(const short8*)&Vt[vo + 32];
        f32x4 o = (dt == 0) ? O0 : (dt == 1) ? O1 : (dt == 2) ? O2 : O3;
        o = __builtin_amdgcn_mfma_f32_16x16x32_bf16(pa0, vb0, o, 0, 0, 0);
        o = __builtin_amdgcn_mfma_f32_16x16x32_bf16(pa1, vb1, o, 0, 0, 0);
        if (dt == 0) O0 = o; else if (dt == 1) O1 = o; else if (dt == 2) O2 = o; else O3 = o;
      }
    }
  }

  // ---- epilogue: normalize, write AO hi/lo bf16 [B,S,E] ----
  {
    const float li0 = 1.f / lstate[0], li1 = 1.f / lstate[1];
    const float li2 = 1.f / lstate[2], li3 = 1.f / lstate[3];
#pragma unroll
    for (int r = 0; r < 4; ++r) {
      const float lir = (r == 0) ? li0 : (r == 1) ? li1 : (r == 2) ? li2 : li3;
      const size_t rowb = (size_t)(b * S_ + q0 + 16 * w + 4 * g + r) * E_ + hh * 64;
      float vals[4];
      vals[0] = O0[r] * lir; vals[1] = O1[r] * lir;
      vals[2] = O2[r] * lir; vals[3] = O3[r] * lir;
#pragma unroll
      for (int c = 0; c < 4; ++c) {
        const u16 h16 = f2bf(vals[c]);
        AOHi[rowb + c * 16 + lc] = h16;
        AOLo[rowb + c * 16 + lc] = f2bf(vals[c] - bf2f(h16));
      }
    }
  }
}

// ---------------------------------------------------------------------------
// Kernel 3: output projection, split-bf16 MFMA. A = AO (pre-split bf16).
// ---------------------------------------------------------------------------
__global__ __launch_bounds__(256) void gemm_out_kernel(
    const u16* __restrict__ AHi, const u16* __restrict__ ALo,
    const u16* __restrict__ WHi, const u16* __restrict__ WLo,
    const float* __restrict__ bias, float* __restrict__ out)
{
  __shared__ __align__(16) short Ah[128 * 40], Al[128 * 40];
  __shared__ __align__(16) short Bh[128 * 40], Bl[128 * 40];

  const int t = threadIdx.x;
  const int m0 = blockIdx.x * 128;
  const int n0 = blockIdx.y * 128;
  const int w = t >> 6, lane = t & 63;
  const int g = lane >> 4, lc = lane & 15;
  const int wm = w & 1, wn = w >> 1;
  const int srow = t >> 1, sh = (t & 1) * 16;

  const u16* Ahb = AHi + (size_t)(m0 + srow) * E_ + sh;
  const u16* Alb = ALo + (size_t)(m0 + srow) * E_ + sh;
  const u16* Bhb = WHi + (size_t)(n0 + srow) * E_ + sh;
  const u16* Blb = WLo + (size_t)(n0 + srow) * E_ + sh;

  f32x4 acc[4][4];
#pragma unroll
  for (int i = 0; i < 4; ++i)
#pragma unroll
    for (int j = 0; j < 4; ++j) acc[i][j] = (f32x4){0.f, 0.f, 0.f, 0.f};

  for (int k0 = 0; k0 < E_; k0 += 32) {
    __syncthreads();
    *(short8*)&Ah[srow * 40 + sh]     = *(const short8*)(Ahb + k0);
    *(short8*)&Ah[srow * 40 + sh + 8] = *(const short8*)(Ahb + k0 + 8);
    *(short8*)&Al[srow * 40 + sh]     = *(const short8*)(Alb + k0);
    *(short8*)&Al[srow * 40 + sh + 8] = *(const short8*)(Alb + k0 + 8);
    *(short8*)&Bh[srow * 40 + sh]     = *(const short8*)(Bhb + k0);
    *(short8*)&Bh[srow * 40 + sh + 8] = *(const short8*)(Bhb + k0 + 8);
    *(short8*)&Bl[srow * 40 + sh]     = *(const short8*)(Blb + k0);
    *(short8*)&Bl[srow * 40 + sh + 8] = *(const short8*)(Blb + k0 + 8);
    __syncthreads();

    short8 ah[4], al[4], bh[4], bl[4];
#pragma unroll
    for (int mt = 0; mt < 4; ++mt) {
      const int ro = (wm * 64 + mt * 16 + lc) * 40 + g * 8;
      ah[mt] = *(const short8*)&Ah[ro];
      al[mt] = *(const short8*)&Al[ro];
    }
#pragma unroll
    for (int nt = 0; nt < 4; ++nt) {
      const int ro = (wn * 64 + nt * 16 + lc) * 40 + g * 8;
      bh[nt] = *(const short8*)&Bh[ro];
      bl[nt] = *(const short8*)&Bl[ro];
    }
#pragma unroll
    for (int mt = 0; mt < 4; ++mt)
#pragma unroll
      for (int nt = 0; nt < 4; ++nt) {
        f32x4 a = acc[mt][nt];
        a = __builtin_amdgcn_mfma_f32_16x16x32_bf16(ah[mt], bh[nt], a, 0, 0, 0);
        a = __builtin_amdgcn_mfma_f32_16x16x32_bf16(ah[mt], bl[nt], a, 0, 0, 0);
        a = __builtin_amdgcn_mfma_f32_16x16x32_bf16(al[mt], bh[nt], a, 0, 0, 0);
        acc[mt][nt] = a;
      }
  }

  float bs[4];
#pragma unroll
  for (int nt = 0; nt < 4; ++nt) bs[nt] = bias[n0 + wn * 64 + nt * 16 + lc];
#pragma unroll
  for (int nt = 0; nt < 4; ++nt) {
    const int nc = n0 + wn * 64 + nt * 16 + lc;
#pragma unroll
    for (int mt = 0; mt < 4; ++mt) {
#pragma unroll
      for (int r = 0; r < 4; ++r) {
        const int mrow = m0 + wm * 64 + mt * 16 + g * 4 + r;
        out[(size_t)mrow * E_ + nc] = acc[mt][nt][r] + bs[nt];
      }
    }
  }
}

// ---------------------------------------------------------------------------
extern "C" void kernel_launch(void* const* d_in, const int* in_sizes, int n_in,
                              void* d_out, int out_size, void* d_ws, size_t ws_size,
                              hipStream_t stream) {
  const float* q    = (const float*)d_in[0];
  const float* k    = (const float*)d_in[1];
  const float* v    = (const float*)d_in[2];
  const int*   mask = (const int*)d_in[3];
  const float* Wqkv = (const float*)d_in[4];
  const float* bqkv = (const float*)d_in[5];
  const float* Wout = (const float*)d_in[6];
  const float* bout = (const float*)d_in[7];
  float* out = (float*)d_out;

  // Workspace layout (64 MB total, proven safe). AO_lo aliases the dead
  // Wqkv hi/lo region (Wqkv conv is consumed entirely by gemm_qkv, which
  // completes before attn launches on the same stream).
  char* wsb = (char*)d_ws;
  u16* WqkvHi = (u16*)(wsb + 0);          //  6 MB
  u16* WqkvLo = (u16*)(wsb + 6291456);    //  6 MB
  u16* WoutHi = (u16*)(wsb + 12582912);   //  2 MB
  u16* WoutLo = (u16*)(wsb + 14680064);   //  2 MB
  u16* QpHi   = (u16*)(wsb + 16777216);   //  8 MB
  u16* QpLo   = (u16*)(wsb + 25165824);   //  8 MB
  u16* KpHi   = (u16*)(wsb + 33554432);   //  8 MB
  u16* KpLo   = (u16*)(wsb + 41943040);   //  8 MB
  u16* Vp     = (u16*)(wsb + 50331648);   //  8 MB
  u16* AOHi   = (u16*)(wsb + 58720256);   //  8 MB
  u16* AOLo   = (u16*)(wsb + 0);          //  8 MB (alias)

  hipLaunchKernelGGL(split_f32_kernel, dim3(3072), dim3(256), 0, stream,
                     Wqkv, WqkvHi, WqkvLo, 786432);
  hipLaunchKernelGGL(split_f32_kernel, dim3(1024), dim3(256), 0, stream,
                     Wout, WoutHi, WoutLo, 262144);
  hipLaunchKernelGGL(gemm_qkv_kernel, dim3(M_ / 128, 24), dim3(256), 0, stream,
                     q, k, v, WqkvHi, WqkvLo, bqkv, QpHi, QpLo, KpHi, KpLo, Vp);
  hipLaunchKernelGGL(attn_mfma_kernel, dim3(S_ / 64, B_ * H_), dim3(256), 0, stream,
                     QpHi, QpLo, KpHi, KpLo, Vp, mask, AOHi, AOLo);
  hipLaunchKernelGGL(gemm_out_kernel, dim3(M_ / 128, E_ / 128), dim3(256), 0, stream,
                     AOHi, AOLo, WoutHi, WoutLo, bout, out);
}

// Round 6
// 381.199 us; speedup vs baseline: 5.3535x; 1.1097x over previous
//
#include <hip/hip_runtime.h>
#include <stdint.h>

// Problem dims (fixed by the reference)
constexpr int B_ = 2, S_ = 2048, E_ = 1024, H_ = 16, D_ = 64;
constexpr int M_ = B_ * S_;              // 4096 rows
constexpr size_t ME_ = (size_t)M_ * E_;  // 4,194,304

typedef unsigned short u16;
typedef __attribute__((ext_vector_type(8))) short short8;
typedef __attribute__((ext_vector_type(4))) float f32x4;

__device__ __forceinline__ float bf2f(u16 u) {
  union { uint32_t i; float f; } v; v.i = ((uint32_t)u) << 16; return v.f;
}
__device__ __forceinline__ u16 f2bf(float f) {
  uint32_t u = __float_as_uint(f);
  return (u16)((u + 0x7FFFu + ((u >> 16) & 1u)) >> 16);  // RNE
}

// ---------------------------------------------------------------------------
// Kernel 0: split fp32 -> (hi, lo) bf16 pair, elementwise (weights).
// ---------------------------------------------------------------------------
__global__ __launch_bounds__(256) void split_f32_kernel(
    const float* __restrict__ src, u16* __restrict__ hi, u16* __restrict__ lo, int n4)
{
  const int i = blockIdx.x * 256 + threadIdx.x;
  if (i >= n4) return;
  const float4 x = ((const float4*)src)[i];
  ushort4 h, l;
  h.x = f2bf(x.x); l.x = f2bf(x.x - bf2f(h.x));
  h.y = f2bf(x.y); l.y = f2bf(x.y - bf2f(h.y));
  h.z = f2bf(x.z); l.z = f2bf(x.z - bf2f(h.z));
  h.w = f2bf(x.w); l.w = f2bf(x.w - bf2f(h.w));
  ((ushort4*)hi)[i] = h;
  ((ushort4*)lo)[i] = l;
}

// ---------------------------------------------------------------------------
// Kernel 1: QKV projection, split-bf16 MFMA (V-proj blocks: single bf16).
// 128x128 tile / block, 4 waves (2x2), each wave 64x64 = 4x4 mfma 16x16x32.
// Epilogue: Q,K -> hi/lo bf16 [B,H,S,D]; V -> bf16 [B,H,D,S] (pre-transposed).
// ---------------------------------------------------------------------------
__global__ __launch_bounds__(256) void gemm_qkv_kernel(
    const float* __restrict__ q, const float* __restrict__ k, const float* __restrict__ v,
    const u16* __restrict__ WHi, const u16* __restrict__ WLo,
    const float* __restrict__ bias,
    u16* __restrict__ QpHi, u16* __restrict__ QpLo,
    u16* __restrict__ KpHi, u16* __restrict__ KpLo,
    u16* __restrict__ Vp)
{
  __shared__ __align__(16) short Ah[128 * 40], Al[128 * 40];
  __shared__ __align__(16) short Bh[128 * 40], Bl[128 * 40];

  const int t = threadIdx.x;
  const int m0 = blockIdx.x * 128;
  const int n0g = blockIdx.y * 128;          // global col in [0, 3072)
  const int proj = n0g >> 10;
  const int nloc = n0g & (E_ - 1);
  const float* A = (proj == 0) ? q : (proj == 1) ? k : v;
  const bool split = (proj < 2);

  const int w = t >> 6, lane = t & 63;
  const int g = lane >> 4, lc = lane & 15;
  const int wm = w & 1, wn = w >> 1;
  const int srow = t >> 1, sh = (t & 1) * 16; // staging: 2 threads/row, 16 elems each

  const float* Ab = A + (size_t)(m0 + srow) * E_ + sh;
  const u16* Bhb = WHi + (size_t)(n0g + srow) * E_ + sh;
  const u16* Blb = WLo + (size_t)(n0g + srow) * E_ + sh;

  f32x4 acc[4][4];
#pragma unroll
  for (int i = 0; i < 4; ++i)
#pragma unroll
    for (int j = 0; j < 4; ++j) acc[i][j] = (f32x4){0.f, 0.f, 0.f, 0.f};

  for (int k0 = 0; k0 < E_; k0 += 32) {
    __syncthreads();
    // stage A: fp32 -> hi/lo bf16
#pragma unroll
    for (int i = 0; i < 4; ++i) {
      const float4 x = *(const float4*)(Ab + k0 + 4 * i);
      ushort4 h, l;
      h.x = f2bf(x.x); l.x = f2bf(x.x - bf2f(h.x));
      h.y = f2bf(x.y); l.y = f2bf(x.y - bf2f(h.y));
      h.z = f2bf(x.z); l.z = f2bf(x.z - bf2f(h.z));
      h.w = f2bf(x.w); l.w = f2bf(x.w - bf2f(h.w));
      *(ushort4*)&Ah[srow * 40 + sh + 4 * i] = h;
      if (split) *(ushort4*)&Al[srow * 40 + sh + 4 * i] = l;
    }
    // stage B hi (and lo only when split)
    {
      *(short8*)&Bh[srow * 40 + sh]     = *(const short8*)(Bhb + k0);
      *(short8*)&Bh[srow * 40 + sh + 8] = *(const short8*)(Bhb + k0 + 8);
      if (split) {
        *(short8*)&Bl[srow * 40 + sh]     = *(const short8*)(Blb + k0);
        *(short8*)&Bl[srow * 40 + sh + 8] = *(const short8*)(Blb + k0 + 8);
      }
    }
    __syncthreads();

    short8 ah[4], al[4], bh[4], bl[4];
#pragma unroll
    for (int mt = 0; mt < 4; ++mt) {
      const int ro = (wm * 64 + mt * 16 + lc) * 40 + g * 8;
      ah[mt] = *(const short8*)&Ah[ro];
      if (split) al[mt] = *(const short8*)&Al[ro];
    }
#pragma unroll
    for (int nt = 0; nt < 4; ++nt) {
      const int ro = (wn * 64 + nt * 16 + lc) * 40 + g * 8;
      bh[nt] = *(const short8*)&Bh[ro];
      if (split) bl[nt] = *(const short8*)&Bl[ro];
    }
#pragma unroll
    for (int mt = 0; mt < 4; ++mt)
#pragma unroll
      for (int nt = 0; nt < 4; ++nt) {
        f32x4 a = acc[mt][nt];
        a = __builtin_amdgcn_mfma_f32_16x16x32_bf16(ah[mt], bh[nt], a, 0, 0, 0);
        if (split) {
          a = __builtin_amdgcn_mfma_f32_16x16x32_bf16(ah[mt], bl[nt], a, 0, 0, 0);
          a = __builtin_amdgcn_mfma_f32_16x16x32_bf16(al[mt], bh[nt], a, 0, 0, 0);
        }
        acc[mt][nt] = a;
      }
  }

  // epilogue
  float bs[4];
#pragma unroll
  for (int nt = 0; nt < 4; ++nt) bs[nt] = bias[n0g + wn * 64 + nt * 16 + lc];

  if (proj < 2) {
    u16* Hi = (proj == 0) ? QpHi : KpHi;
    u16* Lo = (proj == 0) ? QpLo : KpLo;
#pragma unroll
    for (int nt = 0; nt < 4; ++nt) {
      const int nE = nloc + wn * 64 + nt * 16 + lc;
      const int h = nE >> 6, d = nE & 63;
#pragma unroll
      for (int mt = 0; mt < 4; ++mt) {
#pragma unroll
        for (int r = 0; r < 4; ++r) {
          const int mrow = m0 + wm * 64 + mt * 16 + g * 4 + r;
          const int bb = mrow >> 11, s = mrow & (S_ - 1);
          const float val = acc[mt][nt][r] + bs[nt];
          const u16 h16 = f2bf(val);
          const size_t addr = (((size_t)(bb * H_ + h)) * S_ + s) * D_ + d;
          Hi[addr] = h16;
          Lo[addr] = f2bf(val - bf2f(h16));
        }
      }
    }
  } else {
#pragma unroll
    for (int nt = 0; nt < 4; ++nt) {
      const int nE = nloc + wn * 64 + nt * 16 + lc;
      const int h = nE >> 6, d = nE & 63;
#pragma unroll
      for (int mt = 0; mt < 4; ++mt) {
        const int mrow = m0 + wm * 64 + mt * 16 + g * 4;
        const int bb = mrow >> 11, s = mrow & (S_ - 1);
        ushort4 u;
        u.x = f2bf(acc[mt][nt][0] + bs[nt]);
        u.y = f2bf(acc[mt][nt][1] + bs[nt]);
        u.z = f2bf(acc[mt][nt][2] + bs[nt]);
        u.w = f2bf(acc[mt][nt][3] + bs[nt]);
        *(ushort4*)&Vp[(((size_t)(bb * H_ + h)) * D_ + d) * S_ + s] = u;
      }
    }
  }
}

// ---------------------------------------------------------------------------
// Kernel 2: MFMA flash attention v3.
//  128 q-rows / block (4 waves x 2 sets of 16), Q A-frags direct from global.
//  K/V frag ds_reads shared across both q-sets. Softmax denominator computed
//  by MFMA against a ones-column in B (same recurrence as O) — no sum
//  butterfly. Only the max reduction uses shuffles.
// ---------------------------------------------------------------------------
__global__ __launch_bounds__(256) void attn_mfma_kernel(
    const u16* __restrict__ QpHi, const u16* __restrict__ QpLo,
    const u16* __restrict__ KpHi, const u16* __restrict__ KpLo,
    const u16* __restrict__ Vp,
    const int* __restrict__ mask,
    u16* __restrict__ AOHi)
{
  __shared__ __align__(16) short sm[23040];  // 46,080 B
  short* Khi = sm;                           // [64][72]
  short* Klo = sm + 4608;                    // [64][72]
  short* Vt  = sm + 9216;                    // [64][72] (d-major)
  short* Pb  = sm + 13824;                   // 4 waves x 2 sets x [16][72]

  const int t = threadIdx.x;
  const int w = t >> 6, lane = t & 63;
  const int g = lane >> 4, lc = lane & 15;
  const int bh = blockIdx.y;
  const int b = bh >> 4, hh = bh & 15;
  const int q0 = blockIdx.x * 128;
  const size_t hb = (size_t)bh * S_ * D_;
  const u16* QgH = QpHi + hb;
  const u16* QgL = QpLo + hb;
  const u16* KgH = KpHi + hb;
  const u16* KgL = KpLo + hb;
  const u16* Vg  = Vp + hb;
  short* Pw[2] = { Pb + (2 * w + 0) * 1152, Pb + (2 * w + 1) * 1152 };

  // ---- Q A-frags direct from global (lane lc = q-row, k = 8g..8g+7) ----
  short8 qh[2][2], ql[2][2];
#pragma unroll
  for (int s = 0; s < 2; ++s) {
    const size_t base = (size_t)(q0 + 32 * w + 16 * s + lc) * D_ + 8 * g;
    qh[s][0] = *(const short8*)&QgH[base];
    qh[s][1] = *(const short8*)&QgH[base + 32];
    ql[s][0] = *(const short8*)&QgL[base];
    ql[s][1] = *(const short8*)&QgL[base + 32];
  }

  // ones column in B (n=0): lanes with lc==0 hold bf16(1.0) for all k
  short8 ones8 = {0, 0, 0, 0, 0, 0, 0, 0};
  if (lc == 0) {
    const short o = (short)0x3F80;
    ones8 = (short8){o, o, o, o, o, o, o, o};
  }

  f32x4 O[2][4];
  f32x4 Ol[2];
#pragma unroll
  for (int s = 0; s < 2; ++s) {
    Ol[s] = (f32x4){0.f, 0.f, 0.f, 0.f};
#pragma unroll
    for (int dt = 0; dt < 4; ++dt) O[s][dt] = (f32x4){0.f, 0.f, 0.f, 0.f};
  }
  float mst[2][4] = {{-INFINITY, -INFINITY, -INFINITY, -INFINITY},
                     {-INFINITY, -INFINITY, -INFINITY, -INFINITY}};

  const int srow = t >> 2, sc16 = (t & 3) * 16;   // staging: 4 threads/row

  for (int kt = 0; kt < S_; kt += 64) {
    __syncthreads();                         // previous tile fully consumed
    // ---- stage K hi/lo ([key][d]) and V ([d][key]) — pure bf16 copies ----
    *(short8*)&Khi[srow * 72 + sc16]     = *(const short8*)&KgH[(kt + srow) * D_ + sc16];
    *(short8*)&Khi[srow * 72 + sc16 + 8] = *(const short8*)&KgH[(kt + srow) * D_ + sc16 + 8];
    *(short8*)&Klo[srow * 72 + sc16]     = *(const short8*)&KgL[(kt + srow) * D_ + sc16];
    *(short8*)&Klo[srow * 72 + sc16 + 8] = *(const short8*)&KgL[(kt + srow) * D_ + sc16 + 8];
    *(short8*)&Vt[srow * 72 + sc16]      = *(const short8*)&Vg[srow * S_ + kt + sc16];
    *(short8*)&Vt[srow * 72 + sc16 + 8]  = *(const short8*)&Vg[srow * S_ + kt + sc16 + 8];
    int mv[4];
#pragma unroll
    for (int kt16 = 0; kt16 < 4; ++kt16)
      mv[kt16] = mask[b * S_ + kt + 16 * kt16 + lc];
    __syncthreads();

    // ---- scores: S[32q x 64k], K frag reads shared across both q-sets ----
    f32x4 sc[2][4];
#pragma unroll
    for (int kt16 = 0; kt16 < 4; ++kt16) {
      const int ko = (16 * kt16 + lc) * 72 + 8 * g;
      const short8 kh0 = *(const short8*)&Khi[ko];
      const short8 kh1 = *(const short8*)&Khi[ko + 32];
      const short8 kl0 = *(const short8*)&Klo[ko];
      const short8 kl1 = *(const short8*)&Klo[ko + 32];
#pragma unroll
      for (int s = 0; s < 2; ++s) {
        f32x4 a = {0.f, 0.f, 0.f, 0.f};
        a = __builtin_amdgcn_mfma_f32_16x16x32_bf16(qh[s][0], kh0, a, 0, 0, 0);
        a = __builtin_amdgcn_mfma_f32_16x16x32_bf16(qh[s][1], kh1, a, 0, 0, 0);
        a = __builtin_amdgcn_mfma_f32_16x16x32_bf16(qh[s][0], kl0, a, 0, 0, 0);
        a = __builtin_amdgcn_mfma_f32_16x16x32_bf16(qh[s][1], kl1, a, 0, 0, 0);
        a = __builtin_amdgcn_mfma_f32_16x16x32_bf16(ql[s][0], kh0, a, 0, 0, 0);
        a = __builtin_amdgcn_mfma_f32_16x16x32_bf16(ql[s][1], kh1, a, 0, 0, 0);
        sc[s][kt16] = a;
      }
    }

    // ---- mask (key col = 16*kt16 + lc, same for both sets) ----
#pragma unroll
    for (int kt16 = 0; kt16 < 4; ++kt16) {
      if (mv[kt16] == 0) {
#pragma unroll
        for (int s = 0; s < 2; ++s) {
          sc[s][kt16][0] = -1e20f; sc[s][kt16][1] = -1e20f;
          sc[s][kt16][2] = -1e20f; sc[s][kt16][3] = -1e20f;
        }
      }
    }

    // ---- online max + exp (max butterfly only; sum comes from MFMA) ----
    float al[2][4];
#pragma unroll
    for (int s = 0; s < 2; ++s) {
#pragma unroll
      for (int r = 0; r < 4; ++r) {
        float vv = fmaxf(fmaxf(sc[s][0][r], sc[s][1][r]), fmaxf(sc[s][2][r], sc[s][3][r]));
        vv = fmaxf(vv, __shfl_xor(vv, 1));
        vv = fmaxf(vv, __shfl_xor(vv, 2));
        vv = fmaxf(vv, __shfl_xor(vv, 4));
        vv = fmaxf(vv, __shfl_xor(vv, 8));
        const float mn = fmaxf(mst[s][r], vv);
        al[s][r] = __expf(mst[s][r] - mn);   // first tile: exp(-inf)=0
        mst[s][r] = mn;
      }
#pragma unroll
      for (int kt16 = 0; kt16 < 4; ++kt16) {
#pragma unroll
        for (int r = 0; r < 4; ++r)
          sc[s][kt16][r] = __expf(sc[s][kt16][r] - mst[s][r]);
      }
      const f32x4 alv = {al[s][0], al[s][1], al[s][2], al[s][3]};
      O[s][0] *= alv; O[s][1] *= alv; O[s][2] *= alv; O[s][3] *= alv;
      Ol[s] *= alv;
      // P: C-layout regs -> bf16 LDS (A-layout source for PV)
#pragma unroll
      for (int kt16 = 0; kt16 < 4; ++kt16) {
#pragma unroll
        for (int r = 0; r < 4; ++r)
          Pw[s][(4 * g + r) * 72 + 16 * kt16 + lc] = (short)f2bf(sc[s][kt16][r]);
      }
    }

    // ---- PV (V frag reads shared across sets) + denominator via ones ----
    short8 pa[2][2];
#pragma unroll
    for (int s = 0; s < 2; ++s) {
      pa[s][0] = *(const short8*)&Pw[s][lc * 72 + 8 * g];
      pa[s][1] = *(const short8*)&Pw[s][lc * 72 + 32 + 8 * g];
      Ol[s] = __builtin_amdgcn_mfma_f32_16x16x32_bf16(pa[s][0], ones8, Ol[s], 0, 0, 0);
      Ol[s] = __builtin_amdgcn_mfma_f32_16x16x32_bf16(pa[s][1], ones8, Ol[s], 0, 0, 0);
    }
#pragma unroll
    for (int dt = 0; dt < 4; ++dt) {
      const int vo = (16 * dt + lc) * 72 + 8 * g;
      const short8 vb0 = *(const short8*)&Vt[vo];
      const short8 vb1 = *(const short8*)&Vt[vo + 32];
#pragma unroll
      for (int s = 0; s < 2; ++s) {
        O[s][dt] = __builtin_amdgcn_mfma_f32_16x16x32_bf16(pa[s][0], vb0, O[s][dt], 0, 0, 0);
        O[s][dt] = __builtin_amdgcn_mfma_f32_16x16x32_bf16(pa[s][1], vb1, O[s][dt], 0, 0, 0);
      }
    }
  }

  // ---- epilogue: broadcast denominator (col 0 lives on lanes lc==0),
  //      normalize, write AO bf16 [B,S,E] ----
#pragma unroll
  for (int s = 0; s < 2; ++s) {
#pragma unroll
    for (int r = 0; r < 4; ++r) {
      const float lv = __shfl(Ol[s][r], lane & 48);
      const float lir = 1.0f / lv;
      const int qrow = q0 + 32 * w + 16 * s + 4 * g + r;
      const size_t rowb = (size_t)(b * S_ + qrow) * E_ + hh * 64;
#pragma unroll
      for (int dt = 0; dt < 4; ++dt)
        AOHi[rowb + dt * 16 + lc] = f2bf(O[s][dt][r] * lir);
    }
  }
}

// ---------------------------------------------------------------------------
// Kernel 3: output projection, single-bf16 MFMA.
// ---------------------------------------------------------------------------
__global__ __launch_bounds__(256) void gemm_out_kernel(
    const u16* __restrict__ AHi,
    const u16* __restrict__ WHi,
    const float* __restrict__ bias, float* __restrict__ out)
{
  __shared__ __align__(16) short Ah[128 * 40];
  __shared__ __align__(16) short Bh[128 * 40];

  const int t = threadIdx.x;
  const int m0 = blockIdx.x * 128;
  const int n0 = blockIdx.y * 128;
  const int w = t >> 6, lane = t & 63;
  const int g = lane >> 4, lc = lane & 15;
  const int wm = w & 1, wn = w >> 1;
  const int srow = t >> 1, sh = (t & 1) * 16;

  const u16* Ahb = AHi + (size_t)(m0 + srow) * E_ + sh;
  const u16* Bhb = WHi + (size_t)(n0 + srow) * E_ + sh;

  f32x4 acc[4][4];
#pragma unroll
  for (int i = 0; i < 4; ++i)
#pragma unroll
    for (int j = 0; j < 4; ++j) acc[i][j] = (f32x4){0.f, 0.f, 0.f, 0.f};

  for (int k0 = 0; k0 < E_; k0 += 32) {
    __syncthreads();
    *(short8*)&Ah[srow * 40 + sh]     = *(const short8*)(Ahb + k0);
    *(short8*)&Ah[srow * 40 + sh + 8] = *(const short8*)(Ahb + k0 + 8);
    *(short8*)&Bh[srow * 40 + sh]     = *(const short8*)(Bhb + k0);
    *(short8*)&Bh[srow * 40 + sh + 8] = *(const short8*)(Bhb + k0 + 8);
    __syncthreads();

    short8 ah[4], bh[4];
#pragma unroll
    for (int mt = 0; mt < 4; ++mt)
      ah[mt] = *(const short8*)&Ah[(wm * 64 + mt * 16 + lc) * 40 + g * 8];
#pragma unroll
    for (int nt = 0; nt < 4; ++nt)
      bh[nt] = *(const short8*)&Bh[(wn * 64 + nt * 16 + lc) * 40 + g * 8];
#pragma unroll
    for (int mt = 0; mt < 4; ++mt)
#pragma unroll
      for (int nt = 0; nt < 4; ++nt)
        acc[mt][nt] = __builtin_amdgcn_mfma_f32_16x16x32_bf16(ah[mt], bh[nt], acc[mt][nt], 0, 0, 0);
  }

  float bs[4];
#pragma unroll
  for (int nt = 0; nt < 4; ++nt) bs[nt] = bias[n0 + wn * 64 + nt * 16 + lc];
#pragma unroll
  for (int nt = 0; nt < 4; ++nt) {
    const int nc = n0 + wn * 64 + nt * 16 + lc;
#pragma unroll
    for (int mt = 0; mt < 4; ++mt) {
#pragma unroll
      for (int r = 0; r < 4; ++r) {
        const int mrow = m0 + wm * 64 + mt * 16 + g * 4 + r;
        out[(size_t)mrow * E_ + nc] = acc[mt][nt][r] + bs[nt];
      }
    }
  }
}

// ---------------------------------------------------------------------------
extern "C" void kernel_launch(void* const* d_in, const int* in_sizes, int n_in,
                              void* d_out, int out_size, void* d_ws, size_t ws_size,
                              hipStream_t stream) {
  const float* q    = (const float*)d_in[0];
  const float* k    = (const float*)d_in[1];
  const float* v    = (const float*)d_in[2];
  const int*   mask = (const int*)d_in[3];
  const float* Wqkv = (const float*)d_in[4];
  const float* bqkv = (const float*)d_in[5];
  const float* Wout = (const float*)d_in[6];
  const float* bout = (const float*)d_in[7];
  float* out = (float*)d_out;

  // Workspace layout (<= 64 MB, proven safe).
  char* wsb = (char*)d_ws;
  u16* WqkvHi = (u16*)(wsb + 0);          //  6 MB
  u16* WqkvLo = (u16*)(wsb + 6291456);    //  6 MB
  u16* WoutHi = (u16*)(wsb + 12582912);   //  2 MB
  u16* WoutLo = (u16*)(wsb + 14680064);   //  2 MB (unused by gemm_out now)
  u16* QpHi   = (u16*)(wsb + 16777216);   //  8 MB
  u16* QpLo   = (u16*)(wsb + 25165824);   //  8 MB
  u16* KpHi   = (u16*)(wsb + 33554432);   //  8 MB
  u16* KpLo   = (u16*)(wsb + 41943040);   //  8 MB
  u16* Vp     = (u16*)(wsb + 50331648);   //  8 MB
  u16* AOHi   = (u16*)(wsb + 58720256);   //  8 MB

  hipLaunchKernelGGL(split_f32_kernel, dim3(3072), dim3(256), 0, stream,
                     Wqkv, WqkvHi, WqkvLo, 786432);
  hipLaunchKernelGGL(split_f32_kernel, dim3(1024), dim3(256), 0, stream,
                     Wout, WoutHi, WoutLo, 262144);
  hipLaunchKernelGGL(gemm_qkv_kernel, dim3(M_ / 128, 24), dim3(256), 0, stream,
                     q, k, v, WqkvHi, WqkvLo, bqkv, QpHi, QpLo, KpHi, KpLo, Vp);
  hipLaunchKernelGGL(attn_mfma_kernel, dim3(S_ / 128, B_ * H_), dim3(256), 0, stream,
                     QpHi, QpLo, KpHi, KpLo, Vp, mask, AOHi);
  hipLaunchKernelGGL(gemm_out_kernel, dim3(M_ / 128, E_ / 128), dim3(256), 0, stream,
                     AOHi, WoutHi, bout, out);
}

// Round 7
// 333.459 us; speedup vs baseline: 6.1200x; 1.1432x over previous
//
#include <hip/hip_runtime.h>
#include <stdint.h>

// Problem dims (fixed by the reference)
constexpr int B_ = 2, S_ = 2048, E_ = 1024, H_ = 16, D_ = 64;
constexpr int M_ = B_ * S_;              // 4096 rows
constexpr size_t ME_ = (size_t)M_ * E_;  // 4,194,304

typedef unsigned short u16;
typedef __attribute__((ext_vector_type(8))) short short8;
typedef __attribute__((ext_vector_type(4))) float f32x4;

__device__ __forceinline__ float bf2f(u16 u) {
  union { uint32_t i; float f; } v; v.i = ((uint32_t)u) << 16; return v.f;
}
__device__ __forceinline__ u16 f2bf(float f) {
  uint32_t u = __float_as_uint(f);
  return (u16)((u + 0x7FFFu + ((u >> 16) & 1u)) >> 16);  // RNE
}
// truncation split: hi = trunc16(x), lo = trunc16(x - hi). hi+lo ~ x to 2^-17.
__device__ __forceinline__ void tsplit(float x, u16& hi, u16& lo) {
  const uint32_t u = __float_as_uint(x);
  hi = (u16)(u >> 16);
  const float hif = __uint_as_float(u & 0xFFFF0000u);
  lo = (u16)(__float_as_uint(x - hif) >> 16);
}

// ---------------------------------------------------------------------------
// Kernel 0: split fp32 -> (hi, lo) bf16 pair, elementwise (weights).
// ---------------------------------------------------------------------------
__global__ __launch_bounds__(256) void split_f32_kernel(
    const float* __restrict__ src, u16* __restrict__ hi, u16* __restrict__ lo, int n4)
{
  const int i = blockIdx.x * 256 + threadIdx.x;
  if (i >= n4) return;
  const float4 x = ((const float4*)src)[i];
  ushort4 h, l;
  tsplit(x.x, h.x, l.x); tsplit(x.y, h.y, l.y);
  tsplit(x.z, h.z, l.z); tsplit(x.w, h.w, l.w);
  ((ushort4*)hi)[i] = h;
  ((ushort4*)lo)[i] = l;
}

// ---------------------------------------------------------------------------
// Kernel 1: QKV projection, split-bf16 MFMA, register-prefetch pipeline.
// 128x128 tile / block, 4 waves (2x2), each wave 64x64 = 4x4 mfma 16x16x32.
// Epilogue: Q,K via LDS transpose -> b128 row stores (hi & lo passes);
//           V -> bf16 [B,H,D,S] direct (stores fully cover lines).
// ---------------------------------------------------------------------------
__global__ __launch_bounds__(256) void gemm_qkv_kernel(
    const float* __restrict__ q, const float* __restrict__ k, const float* __restrict__ v,
    const u16* __restrict__ WHi, const u16* __restrict__ WLo,
    const float* __restrict__ bias,
    u16* __restrict__ QpHi, u16* __restrict__ QpLo,
    u16* __restrict__ KpHi, u16* __restrict__ KpLo,
    u16* __restrict__ Vp)
{
  __shared__ __align__(16) short smem[20480];  // 40,960 B
  short* Ah = smem;            // 128*40
  short* Al = smem + 5120;
  short* Bh = smem + 10240;
  short* Bl = smem + 15360;

  const int t = threadIdx.x;
  const int m0 = blockIdx.x * 128;
  const int n0g = blockIdx.y * 128;          // global col in [0, 3072)
  const int proj = n0g >> 10;
  const int nloc = n0g & (E_ - 1);
  const float* A = (proj == 0) ? q : (proj == 1) ? k : v;
  const bool split = (proj < 2);

  const int w = t >> 6, lane = t & 63;
  const int g = lane >> 4, lc = lane & 15;
  const int wm = w & 1, wn = w >> 1;
  const int srow = t >> 1, sh = (t & 1) * 16; // staging: 2 threads/row, 16 elems

  const float* Ab = A + (size_t)(m0 + srow) * E_ + sh;
  const u16* Bhb = WHi + (size_t)(n0g + srow) * E_ + sh;
  const u16* Blb = WLo + (size_t)(n0g + srow) * E_ + sh;

  f32x4 acc[4][4];
#pragma unroll
  for (int i = 0; i < 4; ++i)
#pragma unroll
    for (int j = 0; j < 4; ++j) acc[i][j] = (f32x4){0.f, 0.f, 0.f, 0.f};

  // prefetch registers
  float4 ar[4]; short8 br[2], cr[2];
#pragma unroll
  for (int i = 0; i < 4; ++i) ar[i] = *(const float4*)(Ab + 4 * i);
  br[0] = *(const short8*)(Bhb);     br[1] = *(const short8*)(Bhb + 8);
  if (split) { cr[0] = *(const short8*)(Blb); cr[1] = *(const short8*)(Blb + 8); }

  for (int k0 = 0; k0 < E_; k0 += 32) {
    __syncthreads();                 // previous iteration's frag reads done
    // store staged regs -> LDS (A converted hi/lo by truncation split)
#pragma unroll
    for (int i = 0; i < 4; ++i) {
      ushort4 h, l;
      tsplit(ar[i].x, h.x, l.x); tsplit(ar[i].y, h.y, l.y);
      tsplit(ar[i].z, h.z, l.z); tsplit(ar[i].w, h.w, l.w);
      *(ushort4*)&Ah[srow * 40 + sh + 4 * i] = h;
      if (split) *(ushort4*)&Al[srow * 40 + sh + 4 * i] = l;
    }
    *(short8*)&Bh[srow * 40 + sh]     = br[0];
    *(short8*)&Bh[srow * 40 + sh + 8] = br[1];
    if (split) {
      *(short8*)&Bl[srow * 40 + sh]     = cr[0];
      *(short8*)&Bl[srow * 40 + sh + 8] = cr[1];
    }
    __syncthreads();
    // prefetch next K-step (latency hidden behind frag reads + MFMA)
    if (k0 + 32 < E_) {
#pragma unroll
      for (int i = 0; i < 4; ++i) ar[i] = *(const float4*)(Ab + k0 + 32 + 4 * i);
      br[0] = *(const short8*)(Bhb + k0 + 32); br[1] = *(const short8*)(Bhb + k0 + 40);
      if (split) {
        cr[0] = *(const short8*)(Blb + k0 + 32); cr[1] = *(const short8*)(Blb + k0 + 40);
      }
    }

    short8 ah[4], al[4], bh[4], bl[4];
#pragma unroll
    for (int mt = 0; mt < 4; ++mt) {
      const int ro = (wm * 64 + mt * 16 + lc) * 40 + g * 8;
      ah[mt] = *(const short8*)&Ah[ro];
      if (split) al[mt] = *(const short8*)&Al[ro];
    }
#pragma unroll
    for (int nt = 0; nt < 4; ++nt) {
      const int ro = (wn * 64 + nt * 16 + lc) * 40 + g * 8;
      bh[nt] = *(const short8*)&Bh[ro];
      if (split) bl[nt] = *(const short8*)&Bl[ro];
    }
#pragma unroll
    for (int mt = 0; mt < 4; ++mt)
#pragma unroll
      for (int nt = 0; nt < 4; ++nt) {
        f32x4 a = acc[mt][nt];
        a = __builtin_amdgcn_mfma_f32_16x16x32_bf16(ah[mt], bh[nt], a, 0, 0, 0);
        if (split) {
          a = __builtin_amdgcn_mfma_f32_16x16x32_bf16(ah[mt], bl[nt], a, 0, 0, 0);
          a = __builtin_amdgcn_mfma_f32_16x16x32_bf16(al[mt], bh[nt], a, 0, 0, 0);
        }
        acc[mt][nt] = a;
      }
  }

  // epilogue
  float bs[4];
#pragma unroll
  for (int nt = 0; nt < 4; ++nt) bs[nt] = bias[n0g + wn * 64 + nt * 16 + lc];

  if (proj < 2) {
    // each wave's 64 n-cols = exactly one head
    u16* Hi = (proj == 0) ? QpHi : KpHi;
    u16* Lo = (proj == 0) ? QpLo : KpLo;
    const int hwave = (nloc + wn * 64) >> 6;
    short* T = smem + w * 4608;               // per-wave [64][72] u16
    const int mrow = m0 + wm * 64 + lane;
    const int bb = mrow >> 11, s = mrow & (S_ - 1);
    const size_t rowb = (((size_t)(bb * H_ + hwave)) * S_ + s) * D_;
#pragma unroll
    for (int pass = 0; pass < 2; ++pass) {
      __syncthreads();                        // LDS free / prev pass reads done
#pragma unroll
      for (int nt = 0; nt < 4; ++nt)
#pragma unroll
        for (int mt = 0; mt < 4; ++mt)
#pragma unroll
          for (int r = 0; r < 4; ++r) {
            const float val = acc[mt][nt][r] + bs[nt];
            const uint32_t u = __float_as_uint(val);
            u16 x;
            if (pass == 0) x = (u16)(u >> 16);
            else {
              const float hif = __uint_as_float(u & 0xFFFF0000u);
              x = (u16)(__float_as_uint(val - hif) >> 16);
            }
            T[(mt * 16 + g * 4 + r) * 72 + nt * 16 + lc] = (short)x;
          }
      __syncthreads();
      u16* dst = (pass == 0) ? Hi : Lo;
#pragma unroll
      for (int j = 0; j < 8; ++j)
        *(short8*)&dst[rowb + 8 * j] = *(const short8*)&T[lane * 72 + 8 * j];
    }
  } else {
#pragma unroll
    for (int nt = 0; nt < 4; ++nt) {
      const int nE = nloc + wn * 64 + nt * 16 + lc;
      const int h = nE >> 6, d = nE & 63;
#pragma unroll
      for (int mt = 0; mt < 4; ++mt) {
        const int mrow = m0 + wm * 64 + mt * 16 + g * 4;
        const int bb = mrow >> 11, s = mrow & (S_ - 1);
        ushort4 u;
        u.x = f2bf(acc[mt][nt][0] + bs[nt]);
        u.y = f2bf(acc[mt][nt][1] + bs[nt]);
        u.z = f2bf(acc[mt][nt][2] + bs[nt]);
        u.w = f2bf(acc[mt][nt][3] + bs[nt]);
        *(ushort4*)&Vp[(((size_t)(bb * H_ + h)) * D_ + d) * S_ + s] = u;
      }
    }
  }
}

// ---------------------------------------------------------------------------
// Kernel 2: MFMA flash attention v4 (v3 + register-prefetch staging).
// ---------------------------------------------------------------------------
__global__ __launch_bounds__(256) void attn_mfma_kernel(
    const u16* __restrict__ QpHi, const u16* __restrict__ QpLo,
    const u16* __restrict__ KpHi, const u16* __restrict__ KpLo,
    const u16* __restrict__ Vp,
    const int* __restrict__ mask,
    u16* __restrict__ AOHi)
{
  __shared__ __align__(16) short sm[23040];  // 46,080 B
  short* Khi = sm;                           // [64][72]
  short* Klo = sm + 4608;                    // [64][72]
  short* Vt  = sm + 9216;                    // [64][72] (d-major)
  short* Pb  = sm + 13824;                   // 4 waves x 2 sets x [16][72]

  const int t = threadIdx.x;
  const int w = t >> 6, lane = t & 63;
  const int g = lane >> 4, lc = lane & 15;
  const int bh = blockIdx.y;
  const int b = bh >> 4, hh = bh & 15;
  const int q0 = blockIdx.x * 128;
  const size_t hb = (size_t)bh * S_ * D_;
  const u16* QgH = QpHi + hb;
  const u16* QgL = QpLo + hb;
  const u16* KgH = KpHi + hb;
  const u16* KgL = KpLo + hb;
  const u16* Vg  = Vp + hb;
  short* Pw[2] = { Pb + (2 * w + 0) * 1152, Pb + (2 * w + 1) * 1152 };

  // ---- Q A-frags direct from global (lane lc = q-row, k = 8g..8g+7) ----
  short8 qh[2][2], ql[2][2];
#pragma unroll
  for (int s = 0; s < 2; ++s) {
    const size_t base = (size_t)(q0 + 32 * w + 16 * s + lc) * D_ + 8 * g;
    qh[s][0] = *(const short8*)&QgH[base];
    qh[s][1] = *(const short8*)&QgH[base + 32];
    ql[s][0] = *(const short8*)&QgL[base];
    ql[s][1] = *(const short8*)&QgL[base + 32];
  }

  // ones column in B (n=0): lanes with lc==0 hold bf16(1.0) for all k
  short8 ones8 = {0, 0, 0, 0, 0, 0, 0, 0};
  if (lc == 0) {
    const short o = (short)0x3F80;
    ones8 = (short8){o, o, o, o, o, o, o, o};
  }

  f32x4 O[2][4];
  f32x4 Ol[2];
#pragma unroll
  for (int s = 0; s < 2; ++s) {
    Ol[s] = (f32x4){0.f, 0.f, 0.f, 0.f};
#pragma unroll
    for (int dt = 0; dt < 4; ++dt) O[s][dt] = (f32x4){0.f, 0.f, 0.f, 0.f};
  }
  float mst[2][4] = {{-INFINITY, -INFINITY, -INFINITY, -INFINITY},
                     {-INFINITY, -INFINITY, -INFINITY, -INFINITY}};

  const int srow = t >> 2, sc16 = (t & 3) * 16;   // staging: 4 threads/row

  // staging prefetch registers (K hi/lo, V)
  short8 kr[2], lr[2], vr[2];
  kr[0] = *(const short8*)&KgH[srow * D_ + sc16];
  kr[1] = *(const short8*)&KgH[srow * D_ + sc16 + 8];
  lr[0] = *(const short8*)&KgL[srow * D_ + sc16];
  lr[1] = *(const short8*)&KgL[srow * D_ + sc16 + 8];
  vr[0] = *(const short8*)&Vg[srow * S_ + sc16];
  vr[1] = *(const short8*)&Vg[srow * S_ + sc16 + 8];

  for (int kt = 0; kt < S_; kt += 64) {
    __syncthreads();                         // previous tile fully consumed
    *(short8*)&Khi[srow * 72 + sc16]     = kr[0];
    *(short8*)&Khi[srow * 72 + sc16 + 8] = kr[1];
    *(short8*)&Klo[srow * 72 + sc16]     = lr[0];
    *(short8*)&Klo[srow * 72 + sc16 + 8] = lr[1];
    *(short8*)&Vt[srow * 72 + sc16]      = vr[0];
    *(short8*)&Vt[srow * 72 + sc16 + 8]  = vr[1];
    int mv[4];
#pragma unroll
    for (int kt16 = 0; kt16 < 4; ++kt16)
      mv[kt16] = mask[b * S_ + kt + 16 * kt16 + lc];
    __syncthreads();
    if (kt + 64 < S_) {                      // prefetch next tile
      const int kn = kt + 64;
      kr[0] = *(const short8*)&KgH[(kn + srow) * D_ + sc16];
      kr[1] = *(const short8*)&KgH[(kn + srow) * D_ + sc16 + 8];
      lr[0] = *(const short8*)&KgL[(kn + srow) * D_ + sc16];
      lr[1] = *(const short8*)&KgL[(kn + srow) * D_ + sc16 + 8];
      vr[0] = *(const short8*)&Vg[srow * S_ + kn + sc16];
      vr[1] = *(const short8*)&Vg[srow * S_ + kn + sc16 + 8];
    }

    // ---- scores: S[32q x 64k], K frag reads shared across both q-sets ----
    f32x4 sc[2][4];
#pragma unroll
    for (int kt16 = 0; kt16 < 4; ++kt16) {
      const int ko = (16 * kt16 + lc) * 72 + 8 * g;
      const short8 kh0 = *(const short8*)&Khi[ko];
      const short8 kh1 = *(const short8*)&Khi[ko + 32];
      const short8 kl0 = *(const short8*)&Klo[ko];
      const short8 kl1 = *(const short8*)&Klo[ko + 32];
#pragma unroll
      for (int s = 0; s < 2; ++s) {
        f32x4 a = {0.f, 0.f, 0.f, 0.f};
        a = __builtin_amdgcn_mfma_f32_16x16x32_bf16(qh[s][0], kh0, a, 0, 0, 0);
        a = __builtin_amdgcn_mfma_f32_16x16x32_bf16(qh[s][1], kh1, a, 0, 0, 0);
        a = __builtin_amdgcn_mfma_f32_16x16x32_bf16(qh[s][0], kl0, a, 0, 0, 0);
        a = __builtin_amdgcn_mfma_f32_16x16x32_bf16(qh[s][1], kl1, a, 0, 0, 0);
        a = __builtin_amdgcn_mfma_f32_16x16x32_bf16(ql[s][0], kh0, a, 0, 0, 0);
        a = __builtin_amdgcn_mfma_f32_16x16x32_bf16(ql[s][1], kh1, a, 0, 0, 0);
        sc[s][kt16] = a;
      }
    }

    // ---- mask (key col = 16*kt16 + lc, same for both sets) ----
#pragma unroll
    for (int kt16 = 0; kt16 < 4; ++kt16) {
      if (mv[kt16] == 0) {
#pragma unroll
        for (int s = 0; s < 2; ++s) {
          sc[s][kt16][0] = -1e20f; sc[s][kt16][1] = -1e20f;
          sc[s][kt16][2] = -1e20f; sc[s][kt16][3] = -1e20f;
        }
      }
    }

    // ---- online max + exp (max butterfly only; sum comes from MFMA) ----
    float al[2][4];
#pragma unroll
    for (int s = 0; s < 2; ++s) {
#pragma unroll
      for (int r = 0; r < 4; ++r) {
        float vv = fmaxf(fmaxf(sc[s][0][r], sc[s][1][r]), fmaxf(sc[s][2][r], sc[s][3][r]));
        vv = fmaxf(vv, __shfl_xor(vv, 1));
        vv = fmaxf(vv, __shfl_xor(vv, 2));
        vv = fmaxf(vv, __shfl_xor(vv, 4));
        vv = fmaxf(vv, __shfl_xor(vv, 8));
        const float mn = fmaxf(mst[s][r], vv);
        al[s][r] = __expf(mst[s][r] - mn);   // first tile: exp(-inf)=0
        mst[s][r] = mn;
      }
#pragma unroll
      for (int kt16 = 0; kt16 < 4; ++kt16) {
#pragma unroll
        for (int r = 0; r < 4; ++r)
          sc[s][kt16][r] = __expf(sc[s][kt16][r] - mst[s][r]);
      }
      const f32x4 alv = {al[s][0], al[s][1], al[s][2], al[s][3]};
      O[s][0] *= alv; O[s][1] *= alv; O[s][2] *= alv; O[s][3] *= alv;
      Ol[s] *= alv;
      // P: C-layout regs -> bf16 LDS (A-layout source for PV)
#pragma unroll
      for (int kt16 = 0; kt16 < 4; ++kt16) {
#pragma unroll
        for (int r = 0; r < 4; ++r)
          Pw[s][(4 * g + r) * 72 + 16 * kt16 + lc] = (short)f2bf(sc[s][kt16][r]);
      }
    }

    // ---- PV (V frag reads shared across sets) + denominator via ones ----
    short8 pa[2][2];
#pragma unroll
    for (int s = 0; s < 2; ++s) {
      pa[s][0] = *(const short8*)&Pw[s][lc * 72 + 8 * g];
      pa[s][1] = *(const short8*)&Pw[s][lc * 72 + 32 + 8 * g];
      Ol[s] = __builtin_amdgcn_mfma_f32_16x16x32_bf16(pa[s][0], ones8, Ol[s], 0, 0, 0);
      Ol[s] = __builtin_amdgcn_mfma_f32_16x16x32_bf16(pa[s][1], ones8, Ol[s], 0, 0, 0);
    }
#pragma unroll
    for (int dt = 0; dt < 4; ++dt) {
      const int vo = (16 * dt + lc) * 72 + 8 * g;
      const short8 vb0 = *(const short8*)&Vt[vo];
      const short8 vb1 = *(const short8*)&Vt[vo + 32];
#pragma unroll
      for (int s = 0; s < 2; ++s) {
        O[s][dt] = __builtin_amdgcn_mfma_f32_16x16x32_bf16(pa[s][0], vb0, O[s][dt], 0, 0, 0);
        O[s][dt] = __builtin_amdgcn_mfma_f32_16x16x32_bf16(pa[s][1], vb1, O[s][dt], 0, 0, 0);
      }
    }
  }

  // ---- epilogue: broadcast denominator (col 0 on lanes lc==0), normalize ----
#pragma unroll
  for (int s = 0; s < 2; ++s) {
#pragma unroll
    for (int r = 0; r < 4; ++r) {
      const float lv = __shfl(Ol[s][r], lane & 48);
      const float lir = 1.0f / lv;
      const int qrow = q0 + 32 * w + 16 * s + 4 * g + r;
      const size_t rowb = (size_t)(b * S_ + qrow) * E_ + hh * 64;
#pragma unroll
      for (int dt = 0; dt < 4; ++dt)
        AOHi[rowb + dt * 16 + lc] = f2bf(O[s][dt][r] * lir);
    }
  }
}

// ---------------------------------------------------------------------------
// Kernel 3: output projection, single-bf16 MFMA, register prefetch.
// ---------------------------------------------------------------------------
__global__ __launch_bounds__(256) void gemm_out_kernel(
    const u16* __restrict__ AHi,
    const u16* __restrict__ WHi,
    const float* __restrict__ bias, float* __restrict__ out)
{
  __shared__ __align__(16) short Ah[128 * 40];
  __shared__ __align__(16) short Bh[128 * 40];

  const int t = threadIdx.x;
  const int m0 = blockIdx.x * 128;
  const int n0 = blockIdx.y * 128;
  const int w = t >> 6, lane = t & 63;
  const int g = lane >> 4, lc = lane & 15;
  const int wm = w & 1, wn = w >> 1;
  const int srow = t >> 1, sh = (t & 1) * 16;

  const u16* Ahb = AHi + (size_t)(m0 + srow) * E_ + sh;
  const u16* Bhb = WHi + (size_t)(n0 + srow) * E_ + sh;

  f32x4 acc[4][4];
#pragma unroll
  for (int i = 0; i < 4; ++i)
#pragma unroll
    for (int j = 0; j < 4; ++j) acc[i][j] = (f32x4){0.f, 0.f, 0.f, 0.f};

  short8 arr[2], brr[2];
  arr[0] = *(const short8*)(Ahb); arr[1] = *(const short8*)(Ahb + 8);
  brr[0] = *(const short8*)(Bhb); brr[1] = *(const short8*)(Bhb + 8);

  for (int k0 = 0; k0 < E_; k0 += 32) {
    __syncthreads();
    *(short8*)&Ah[srow * 40 + sh]     = arr[0];
    *(short8*)&Ah[srow * 40 + sh + 8] = arr[1];
    *(short8*)&Bh[srow * 40 + sh]     = brr[0];
    *(short8*)&Bh[srow * 40 + sh + 8] = brr[1];
    __syncthreads();
    if (k0 + 32 < E_) {
      arr[0] = *(const short8*)(Ahb + k0 + 32); arr[1] = *(const short8*)(Ahb + k0 + 40);
      brr[0] = *(const short8*)(Bhb + k0 + 32); brr[1] = *(const short8*)(Bhb + k0 + 40);
    }

    short8 ah[4], bh[4];
#pragma unroll
    for (int mt = 0; mt < 4; ++mt)
      ah[mt] = *(const short8*)&Ah[(wm * 64 + mt * 16 + lc) * 40 + g * 8];
#pragma unroll
    for (int nt = 0; nt < 4; ++nt)
      bh[nt] = *(const short8*)&Bh[(wn * 64 + nt * 16 + lc) * 40 + g * 8];
#pragma unroll
    for (int mt = 0; mt < 4; ++mt)
#pragma unroll
      for (int nt = 0; nt < 4; ++nt)
        acc[mt][nt] = __builtin_amdgcn_mfma_f32_16x16x32_bf16(ah[mt], bh[nt], acc[mt][nt], 0, 0, 0);
  }

  float bs[4];
#pragma unroll
  for (int nt = 0; nt < 4; ++nt) bs[nt] = bias[n0 + wn * 64 + nt * 16 + lc];
#pragma unroll
  for (int nt = 0; nt < 4; ++nt) {
    const int nc = n0 + wn * 64 + nt * 16 + lc;
#pragma unroll
    for (int mt = 0; mt < 4; ++mt) {
#pragma unroll
      for (int r = 0; r < 4; ++r) {
        const int mrow = m0 + wm * 64 + mt * 16 + g * 4 + r;
        out[(size_t)mrow * E_ + nc] = acc[mt][nt][r] + bs[nt];
      }
    }
  }
}

// ---------------------------------------------------------------------------
extern "C" void kernel_launch(void* const* d_in, const int* in_sizes, int n_in,
                              void* d_out, int out_size, void* d_ws, size_t ws_size,
                              hipStream_t stream) {
  const float* q    = (const float*)d_in[0];
  const float* k    = (const float*)d_in[1];
  const float* v    = (const float*)d_in[2];
  const int*   mask = (const int*)d_in[3];
  const float* Wqkv = (const float*)d_in[4];
  const float* bqkv = (const float*)d_in[5];
  const float* Wout = (const float*)d_in[6];
  const float* bout = (const float*)d_in[7];
  float* out = (float*)d_out;

  // Workspace layout (<= 64 MB, proven safe).
  char* wsb = (char*)d_ws;
  u16* WqkvHi = (u16*)(wsb + 0);          //  6 MB
  u16* WqkvLo = (u16*)(wsb + 6291456);    //  6 MB
  u16* WoutHi = (u16*)(wsb + 12582912);   //  2 MB
  u16* WoutLo = (u16*)(wsb + 14680064);   //  2 MB (unused)
  u16* QpHi   = (u16*)(wsb + 16777216);   //  8 MB
  u16* QpLo   = (u16*)(wsb + 25165824);   //  8 MB
  u16* KpHi   = (u16*)(wsb + 33554432);   //  8 MB
  u16* KpLo   = (u16*)(wsb + 41943040);   //  8 MB
  u16* Vp     = (u16*)(wsb + 50331648);   //  8 MB
  u16* AOHi   = (u16*)(wsb + 58720256);   //  8 MB

  hipLaunchKernelGGL(split_f32_kernel, dim3(3072), dim3(256), 0, stream,
                     Wqkv, WqkvHi, WqkvLo, 786432);
  hipLaunchKernelGGL(split_f32_kernel, dim3(1024), dim3(256), 0, stream,
                     Wout, WoutHi, WoutLo, 262144);
  hipLaunchKernelGGL(gemm_qkv_kernel, dim3(M_ / 128, 24), dim3(256), 0, stream,
                     q, k, v, WqkvHi, WqkvLo, bqkv, QpHi, QpLo, KpHi, KpLo, Vp);
  hipLaunchKernelGGL(attn_mfma_kernel, dim3(S_ / 128, B_ * H_), dim3(256), 0, stream,
                     QpHi, QpLo, KpHi, KpLo, Vp, mask, AOHi);
  hipLaunchKernelGGL(gemm_out_kernel, dim3(M_ / 128, E_ / 128), dim3(256), 0, stream,
                     AOHi, WoutHi, bout, out);
}